// Round 8
// baseline (376.726 us; speedup 1.0000x reference)
//
#include <hip/hip_runtime.h>

#define N_NODES 65536
#define N_EDGES 1048576
#define NBUCK 256                 // coarse buckets (dst>>8), 256 nodes each
#define PBLOCKS 256               // partition blocks
#define EPB (N_EDGES / PBLOCKS)   // 4096 edges per partition block
#define K4CAP 6144                // finalize LDS staging capacity (mean 4096, sigma 64)
constexpr float NEG = 0.2f;
constexpr float EPS_ = 1e-16f;

typedef __attribute__((ext_vector_type(8))) short bf16x8;
typedef __attribute__((ext_vector_type(4))) float f32x4;

// bf16 helpers (bit tricks; no NaN inputs here)
__device__ __forceinline__ unsigned short f2bf(float f) {
    unsigned int u = __float_as_uint(f);
    return (unsigned short)((u + 0x7fffu + ((u >> 16) & 1u)) >> 16);
}
__device__ __forceinline__ float bflo(unsigned int p) { return __uint_as_float(p << 16); }
__device__ __forceinline__ float bfhi(unsigned int p) { return __uint_as_float(p & 0xffff0000u); }
__device__ __forceinline__ float bf2f(unsigned short u) { return __uint_as_float((unsigned int)u << 16); }
__device__ __forceinline__ float lrelu_exp(float l) { return __expf(fmaxf(l, NEG * l)); }

// ---------------- CSR build: radix partition by dst>>8, no global atomics ----------------

__global__ __launch_bounds__(256) void coarse_hist(const int* __restrict__ ei,
                                                   int* __restrict__ hist_mat) {
    __shared__ int h[NBUCK];
    int t = threadIdx.x;
    h[t] = 0;
    __syncthreads();
    int base = blockIdx.x * EPB;
    #pragma unroll
    for (int i = 0; i < EPB / 256; ++i) {
        int d = ei[N_EDGES + base + i * 256 + t];
        atomicAdd(&h[d >> 8], 1);
    }
    __syncthreads();
    hist_mat[t * PBLOCKS + blockIdx.x] = h[t];
}

__global__ __launch_bounds__(1024) void scan_a(const int* __restrict__ in,
                                               int* __restrict__ out,
                                               int* __restrict__ bsum) {
    __shared__ int sm[1024];
    int t = threadIdx.x, i = blockIdx.x * 1024 + t;
    int v = in[i];
    sm[t] = v;
    __syncthreads();
    for (int off = 1; off < 1024; off <<= 1) {
        int u = (t >= off) ? sm[t - off] : 0;
        __syncthreads();
        sm[t] += u;
        __syncthreads();
    }
    out[i] = sm[t] - v;
    if (t == 1023) bsum[blockIdx.x] = sm[t];
}

__global__ __launch_bounds__(64) void scan_b(int* __restrict__ bsum,
                                             int* __restrict__ row_ptr) {
    int t = threadIdx.x;
    int v = bsum[t];
    int incl = v;
    #pragma unroll
    for (int off = 1; off < 64; off <<= 1) {
        int u = __shfl_up(incl, off);
        if (t >= off) incl += u;
    }
    bsum[t] = incl - v;
    if (t == 63) row_ptr[N_NODES] = incl;   // == N_EDGES
}

__global__ __launch_bounds__(1024) void scan_c(int* __restrict__ arr,
                                               const int* __restrict__ bsum) {
    int i = blockIdx.x * 1024 + threadIdx.x;
    arr[i] += bsum[blockIdx.x];
}

__global__ __launch_bounds__(256) void partition_kernel(const int* __restrict__ ei,
                                                        const int* __restrict__ cursor_mat,
                                                        unsigned int* __restrict__ edge_part) {
    __shared__ int h[NBUCK];
    __shared__ int start[NBUCK];
    __shared__ int cur[NBUCK];
    __shared__ int gcur[NBUCK];
    __shared__ unsigned int stage[EPB];
    int t = threadIdx.x;
    h[t] = 0;
    gcur[t] = cursor_mat[t * PBLOCKS + blockIdx.x];
    __syncthreads();
    unsigned int ent[EPB / 256];
    int base = blockIdx.x * EPB;
    #pragma unroll
    for (int i = 0; i < EPB / 256; ++i) {
        int e = base + i * 256 + t;
        int s = ei[e], d = ei[N_EDGES + e];
        ent[i] = ((unsigned int)s << 16) | (unsigned int)d;   // src,dst both < 2^16
        atomicAdd(&h[d >> 8], 1);
    }
    __syncthreads();
    int v = h[t];
    start[t] = v;
    __syncthreads();
    for (int off = 1; off < 256; off <<= 1) {
        int u = (t >= off) ? start[t - off] : 0;
        __syncthreads();
        start[t] += u;
        __syncthreads();
    }
    int excl = start[t] - v;
    start[t] = excl;
    cur[t] = excl;
    __syncthreads();
    #pragma unroll
    for (int i = 0; i < EPB / 256; ++i) {
        int b = (int)((ent[i] & 0xffffu) >> 8);
        int slot = atomicAdd(&cur[b], 1);
        stage[slot] = ent[i];
    }
    __syncthreads();
    int s0 = t * (EPB / 256);
    #pragma unroll
    for (int i = 0; i < EPB / 256; ++i) {
        unsigned int p = stage[s0 + i];
        int b = (int)((p & 0xffffu) >> 8);
        edge_part[gcur[b] + (s0 + i - start[b])] = p;
    }
}

__global__ __launch_bounds__(256) void finalize_kernel(const unsigned int* __restrict__ edge_part,
                                                       const int* __restrict__ cursor_mat,
                                                       int* __restrict__ row_ptr,
                                                       int* __restrict__ csr_src) {
    __shared__ int h[256];
    __shared__ int sc[256];
    __shared__ int cur[256];
    __shared__ unsigned short stage[K4CAP];
    int t = threadIdx.x;
    int b = blockIdx.x;
    int cs = cursor_mat[b * PBLOCKS];
    int ce = (b == NBUCK - 1) ? N_EDGES : cursor_mat[(b + 1) * PBLOCKS];
    int cnt = ce - cs;
    h[t] = 0;
    __syncthreads();
    for (int i = t; i < cnt; i += 256)
        atomicAdd(&h[edge_part[cs + i] & 0xffu], 1);
    __syncthreads();
    int v = h[t];
    sc[t] = v;
    __syncthreads();
    for (int off = 1; off < 256; off <<= 1) {
        int u = (t >= off) ? sc[t - off] : 0;
        __syncthreads();
        sc[t] += u;
        __syncthreads();
    }
    int excl = sc[t] - v;
    row_ptr[b * 256 + t] = cs + excl;
    cur[t] = excl;
    __syncthreads();
    if (cnt <= K4CAP) {
        for (int i = t; i < cnt; i += 256) {
            unsigned int p = edge_part[cs + i];
            int slot = atomicAdd(&cur[p & 0xffu], 1);
            stage[slot] = (unsigned short)(p >> 16);
        }
        __syncthreads();
        for (int i = t; i < cnt; i += 256)
            csr_src[cs + i] = (int)stage[i];
    } else {
        for (int i = t; i < cnt; i += 256) {
            unsigned int p = edge_part[cs + i];
            int slot = atomicAdd(&cur[p & 0xffu], 1);
            csr_src[cs + slot] = (int)(p >> 16);
        }
    }
}

// ---------------- GEMM via MFMA 16x16x32 bf16 (fp32 accum, bf16 out) ----------------
// block = 256 thr = 4 waves = 64 nodes; W pre-swizzled in LDS to B-frag layout.
// A: lane holds A[m=lane&15][k=quad*8+j]; C/D: col=lane&15, row=quad*4+reg.

template <int OUTC>
__global__ __launch_bounds__(256) void gemm_mfma(const float* __restrict__ X,
                                                 const float* __restrict__ W,
                                                 unsigned short* __restrict__ H) {
    constexpr int NT = OUTC / 16;          // 16-wide col tiles
    extern __shared__ unsigned short Wl[]; // [NT*4][64][8] bf16 frag-ordered
    int t = threadIdx.x;
    for (int idx = t; idx < OUTC * 128; idx += 256) {
        int j = idx & 7;
        int ln = (idx >> 3) & 63;
        int fc = idx >> 9;                 // frag = ct*4 + kc
        int kc = fc & 3, ct = fc >> 2;
        int k = kc * 32 + (ln >> 4) * 8 + j;
        int n = ct * 16 + (ln & 15);
        Wl[idx] = (unsigned short)f2bf(W[k * OUTC + n]);
    }
    __syncthreads();
    int wave = t >> 6, lane = t & 63;
    int m = lane & 15, quad = lane >> 4;
    int node_base = blockIdx.x * 64 + wave * 16;
    const float* xrow = X + (size_t)(node_base + m) * 128 + quad * 8;
    bf16x8 a[4];
    #pragma unroll
    for (int kc = 0; kc < 4; ++kc) {
        float4 u = *(const float4*)(xrow + kc * 32);
        float4 v = *(const float4*)(xrow + kc * 32 + 4);
        bf16x8 af;
        af[0] = (short)f2bf(u.x); af[1] = (short)f2bf(u.y);
        af[2] = (short)f2bf(u.z); af[3] = (short)f2bf(u.w);
        af[4] = (short)f2bf(v.x); af[5] = (short)f2bf(v.y);
        af[6] = (short)f2bf(v.z); af[7] = (short)f2bf(v.w);
        a[kc] = af;
    }
    #pragma unroll
    for (int ct = 0; ct < NT; ++ct) {
        f32x4 acc = {0.f, 0.f, 0.f, 0.f};
        #pragma unroll
        for (int kc = 0; kc < 4; ++kc) {
            bf16x8 bfr = *(const bf16x8*)(Wl + ((ct * 4 + kc) * 64 + lane) * 8);
            acc = __builtin_amdgcn_mfma_f32_16x16x32_bf16(a[kc], bfr, acc, 0, 0, 0);
        }
        #pragma unroll
        for (int r = 0; r < 4; ++r) {
            int row = quad * 4 + r;
            H[(size_t)(node_base + row) * OUTC + ct * 16 + m] = (unsigned short)f2bf(acc[r]);
        }
    }
}

// ---------------- attention logits (bf16 h) ----------------

__global__ __launch_bounds__(256) void att1_kernel(const unsigned int* __restrict__ h1u,
                                                   const float* __restrict__ as_w,
                                                   const float* __restrict__ ad_w,
                                                   float* __restrict__ a_src,
                                                   float* __restrict__ a_dst) {
    int wave = (blockIdx.x * 256 + threadIdx.x) >> 6;
    int lane = threadIdx.x & 63;
    unsigned int p = h1u[wave * 64 + lane];
    float h0 = bflo(p), h1v = bfhi(p);
    float2 sw = *(const float2*)(as_w + lane * 2);
    float2 dw = *(const float2*)(ad_w + lane * 2);
    float ps = h0 * sw.x + h1v * sw.y;
    float pd = h0 * dw.x + h1v * dw.y;
    #pragma unroll
    for (int m = 1; m < 16; m <<= 1) {
        ps += __shfl_xor(ps, m);
        pd += __shfl_xor(pd, m);
    }
    if ((lane & 15) == 0) {
        a_src[wave * 4 + (lane >> 4)] = ps;
        a_dst[wave * 4 + (lane >> 4)] = pd;
    }
}

__global__ __launch_bounds__(256) void att2_kernel(const unsigned short* __restrict__ h2u,
                                                   const float* __restrict__ as_w,
                                                   const float* __restrict__ ad_w,
                                                   float* __restrict__ a_src,
                                                   float* __restrict__ a_dst) {
    int wave = (blockIdx.x * 256 + threadIdx.x) >> 6;
    int lane = threadIdx.x & 63;
    float v = bf2f(h2u[wave * 64 + lane]);
    float ps = v * as_w[lane];
    float pd = v * ad_w[lane];
    #pragma unroll
    for (int m = 1; m < 64; m <<= 1) {
        ps += __shfl_xor(ps, m);
        pd += __shfl_xor(pd, m);
    }
    if (lane == 0) {
        a_src[wave] = ps;
        a_dst[wave] = pd;
    }
}

// ---------------- edge aggregation (softmax fused, shared w via shfl) ----------------
// agg1: wave per dst; per 16-edge batch the 64 lanes compute all 16edges x 4heads
// weights once (lane = (edge lane&15, head lane>>4) == its own head), then shfl.

__global__ __launch_bounds__(256) void agg1_kernel(const int* __restrict__ row_ptr,
                                                   const int* __restrict__ csr_src,
                                                   const unsigned int* __restrict__ h1u,
                                                   const float* __restrict__ a_src,
                                                   const float* __restrict__ a_dst,
                                                   const float* __restrict__ b1,
                                                   float* __restrict__ x2) {
    int n = (blockIdx.x * 256 + threadIdx.x) >> 6;
    int lane = threadIdx.x & 63;
    int hd = lane >> 4;
    int j16 = lane & 15;
    int wbase = lane & 48;
    int c0 = lane * 2;
    float ad = a_dst[n * 4 + hd];
    int e = row_ptr[n], end = row_ptr[n + 1];
    float acc0 = 0.f, acc1 = 0.f, denom = 0.f;
    while (e + 16 <= end) {
        int s_l = csr_src[e + j16];                        // edge j16's src (quads redundant)
        float wv = lrelu_exp(a_src[s_l * 4 + hd] + ad);    // w(edge j16, head hd)
        #pragma unroll
        for (int j = 0; j < 16; ++j) {
            int s = __shfl(s_l, j);
            float w = __shfl(wv, wbase + j);
            unsigned int p = h1u[(size_t)s * 64 + lane];
            denom += w;
            acc0 += w * bflo(p);
            acc1 += w * bfhi(p);
        }
        e += 16;
    }
    int mb = end - e;
    if (mb > 0) {
        int s_l = csr_src[e + (j16 < mb ? j16 : 0)];
        float wv = lrelu_exp(a_src[s_l * 4 + hd] + ad);
        for (int j = 0; j < mb; ++j) {
            int s = __shfl(s_l, j);
            float w = __shfl(wv, wbase + j);
            unsigned int p = h1u[(size_t)s * 64 + lane];
            denom += w;
            acc0 += w * bflo(p);
            acc1 += w * bfhi(p);
        }
    }
    float inv = 1.f / (denom + EPS_);
    float o0 = acc0 * inv + b1[c0];
    float o1 = acc1 * inv + b1[c0 + 1];
    o0 = 1.f / (1.f + __expf(-o0));
    o1 = 1.f / (1.f + __expf(-o1));
    *(float2*)(x2 + (size_t)n * 128 + c0) = make_float2(o0, o1);
}

__global__ __launch_bounds__(256) void agg2_kernel(const int* __restrict__ row_ptr,
                                                   const int* __restrict__ csr_src,
                                                   const unsigned short* __restrict__ h2u,
                                                   const float* __restrict__ a_src,
                                                   const float* __restrict__ a_dst,
                                                   const float* __restrict__ b2,
                                                   float* __restrict__ out) {
    int n = (blockIdx.x * 256 + threadIdx.x) >> 6;
    int lane = threadIdx.x & 63;
    float ad = a_dst[n];
    int e = row_ptr[n], end = row_ptr[n + 1];
    float acc = 0.f, denom = 0.f;
    while (e + 64 <= end) {
        int s_l = csr_src[e + lane];
        float wv = lrelu_exp(a_src[s_l] + ad);             // w(edge lane)
        #pragma unroll
        for (int b = 0; b < 4; ++b) {
            #pragma unroll
            for (int j = 0; j < 16; ++j) {
                int src_lane = b * 16 + j;
                int s = __shfl(s_l, src_lane);
                float w = __shfl(wv, src_lane);
                denom += w;
                acc += w * bf2f(h2u[(size_t)s * 64 + lane]);
            }
        }
        e += 64;
    }
    int mb = end - e;
    if (mb > 0) {
        int s_l = csr_src[e + (lane < mb ? lane : 0)];
        float wv = lrelu_exp(a_src[s_l] + ad);
        for (int j = 0; j < mb; ++j) {
            int s = __shfl(s_l, j);
            float w = __shfl(wv, j);
            denom += w;
            acc += w * bf2f(h2u[(size_t)s * 64 + lane]);
        }
    }
    float o = acc / (denom + EPS_) + b2[lane];
    out[(size_t)n * 64 + lane] = 1.f / (1.f + __expf(-o));
}

// ---------------- launch ----------------

extern "C" void kernel_launch(void* const* d_in, const int* in_sizes, int n_in,
                              void* d_out, int out_size, void* d_ws, size_t ws_size,
                              hipStream_t stream) {
    (void)in_sizes; (void)n_in; (void)out_size; (void)ws_size;
    const float* x   = (const float*)d_in[0];
    const int*   ei  = (const int*)d_in[1];
    const float* W1  = (const float*)d_in[2];
    const float* as1 = (const float*)d_in[3];
    const float* ad1 = (const float*)d_in[4];
    const float* b1  = (const float*)d_in[5];
    const float* W2  = (const float*)d_in[6];
    const float* as2 = (const float*)d_in[7];
    const float* ad2 = (const float*)d_in[8];
    const float* b2  = (const float*)d_in[9];
    float* out = (float*)d_out;

    char* p = (char*)d_ws;
    auto alloc = [&](size_t bytes) -> void* {
        void* r = (void*)p;
        p += (bytes + 255) & ~(size_t)255;
        return r;
    };
    int* hist_mat   = (int*)alloc((size_t)NBUCK * PBLOCKS * 4);
    int* cursor_mat = (int*)alloc((size_t)NBUCK * PBLOCKS * 4);
    int* bsum       = (int*)alloc(64 * 4);
    unsigned int* edge_part = (unsigned int*)alloc((size_t)N_EDGES * 4);
    int* row_ptr    = (int*)alloc((size_t)(N_NODES + 1) * 4);
    int* csr_src    = (int*)alloc((size_t)N_EDGES * 4);
    unsigned short* h1 = (unsigned short*)alloc((size_t)N_NODES * 128 * 2);
    float* a_src1   = (float*)alloc((size_t)N_NODES * 4 * 4);
    float* a_dst1   = (float*)alloc((size_t)N_NODES * 4 * 4);
    float* x2       = (float*)alloc((size_t)N_NODES * 128 * 4);
    unsigned short* h2 = (unsigned short*)alloc((size_t)N_NODES * 64 * 2);
    float* a_src2   = (float*)alloc((size_t)N_NODES * 4);
    float* a_dst2   = (float*)alloc((size_t)N_NODES * 4);

    // CSR build (atomic-free radix partition)
    coarse_hist<<<PBLOCKS, 256, 0, stream>>>(ei, hist_mat);
    scan_a<<<64, 1024, 0, stream>>>(hist_mat, cursor_mat, bsum);
    scan_b<<<1, 64, 0, stream>>>(bsum, row_ptr);
    scan_c<<<64, 1024, 0, stream>>>(cursor_mat, bsum);
    partition_kernel<<<PBLOCKS, 256, 0, stream>>>(ei, cursor_mat, edge_part);
    finalize_kernel<<<NBUCK, 256, 0, stream>>>(edge_part, cursor_mat, row_ptr, csr_src);

    // layer 1
    gemm_mfma<128><<<N_NODES / 64, 256, 128 * 128 * 2, stream>>>(x, W1, h1);
    att1_kernel<<<N_NODES / 4, 256, 0, stream>>>((const unsigned int*)h1, as1, ad1, a_src1, a_dst1);
    agg1_kernel<<<N_NODES / 4, 256, 0, stream>>>(row_ptr, csr_src, (const unsigned int*)h1,
                                                 a_src1, a_dst1, b1, x2);

    // layer 2
    gemm_mfma<64><<<N_NODES / 64, 256, 128 * 64 * 2, stream>>>(x2, W2, h2);
    att2_kernel<<<N_NODES / 4, 256, 0, stream>>>(h2, as2, ad2, a_src2, a_dst2);
    agg2_kernel<<<N_NODES / 4, 256, 0, stream>>>(row_ptr, csr_src, h2, a_src2, a_dst2, b2, out);
}

// Round 9
// 274.197 us; speedup vs baseline: 1.3739x; 1.3739x over previous
//
#include <hip/hip_runtime.h>

#define N_NODES 65536
#define N_EDGES 1048576
#define NBUCK 256                 // coarse buckets (dst>>8), 256 nodes each
#define PBLOCKS 256               // partition blocks
#define EPB (N_EDGES / PBLOCKS)   // 4096 edges per partition block
#define K4CAP 6144                // finalize LDS staging capacity (mean 4096, sigma 64)
constexpr float NEG = 0.2f;
constexpr float EPS_ = 1e-16f;

typedef __attribute__((ext_vector_type(8))) short bf16x8;
typedef __attribute__((ext_vector_type(4))) float f32x4;

// bf16 helpers (bit tricks; no NaN inputs here)
__device__ __forceinline__ unsigned short f2bf(float f) {
    unsigned int u = __float_as_uint(f);
    return (unsigned short)((u + 0x7fffu + ((u >> 16) & 1u)) >> 16);
}
__device__ __forceinline__ float bflo(unsigned int p) { return __uint_as_float(p << 16); }
__device__ __forceinline__ float bfhi(unsigned int p) { return __uint_as_float(p & 0xffff0000u); }
__device__ __forceinline__ float bf2f(unsigned short u) { return __uint_as_float((unsigned int)u << 16); }
__device__ __forceinline__ float lrelu_exp(float l) { return __expf(fmaxf(l, NEG * l)); }

// ---------------- CSR build: radix partition by dst>>8, no global atomics ----------------

__global__ __launch_bounds__(256) void coarse_hist(const int* __restrict__ ei,
                                                   int* __restrict__ hist_mat) {
    __shared__ int h[NBUCK];
    int t = threadIdx.x;
    h[t] = 0;
    __syncthreads();
    int base = blockIdx.x * EPB;
    #pragma unroll
    for (int i = 0; i < EPB / 256; ++i) {
        int d = ei[N_EDGES + base + i * 256 + t];
        atomicAdd(&h[d >> 8], 1);
    }
    __syncthreads();
    hist_mat[t * PBLOCKS + blockIdx.x] = h[t];
}

__global__ __launch_bounds__(1024) void scan_a(const int* __restrict__ in,
                                               int* __restrict__ out,
                                               int* __restrict__ bsum) {
    __shared__ int sm[1024];
    int t = threadIdx.x, i = blockIdx.x * 1024 + t;
    int v = in[i];
    sm[t] = v;
    __syncthreads();
    for (int off = 1; off < 1024; off <<= 1) {
        int u = (t >= off) ? sm[t - off] : 0;
        __syncthreads();
        sm[t] += u;
        __syncthreads();
    }
    out[i] = sm[t] - v;
    if (t == 1023) bsum[blockIdx.x] = sm[t];
}

__global__ __launch_bounds__(64) void scan_b(int* __restrict__ bsum,
                                             int* __restrict__ row_ptr) {
    int t = threadIdx.x;
    int v = bsum[t];
    int incl = v;
    #pragma unroll
    for (int off = 1; off < 64; off <<= 1) {
        int u = __shfl_up(incl, off);
        if (t >= off) incl += u;
    }
    bsum[t] = incl - v;
    if (t == 63) row_ptr[N_NODES] = incl;   // == N_EDGES
}

__global__ __launch_bounds__(1024) void scan_c(int* __restrict__ arr,
                                               const int* __restrict__ bsum) {
    int i = blockIdx.x * 1024 + threadIdx.x;
    arr[i] += bsum[blockIdx.x];
}

__global__ __launch_bounds__(256) void partition_kernel(const int* __restrict__ ei,
                                                        const int* __restrict__ cursor_mat,
                                                        unsigned int* __restrict__ edge_part) {
    __shared__ int h[NBUCK];
    __shared__ int start[NBUCK];
    __shared__ int cur[NBUCK];
    __shared__ int gcur[NBUCK];
    __shared__ unsigned int stage[EPB];
    int t = threadIdx.x;
    h[t] = 0;
    gcur[t] = cursor_mat[t * PBLOCKS + blockIdx.x];
    __syncthreads();
    unsigned int ent[EPB / 256];
    int base = blockIdx.x * EPB;
    #pragma unroll
    for (int i = 0; i < EPB / 256; ++i) {
        int e = base + i * 256 + t;
        int s = ei[e], d = ei[N_EDGES + e];
        ent[i] = ((unsigned int)s << 16) | (unsigned int)d;   // src,dst both < 2^16
        atomicAdd(&h[d >> 8], 1);
    }
    __syncthreads();
    int v = h[t];
    start[t] = v;
    __syncthreads();
    for (int off = 1; off < 256; off <<= 1) {
        int u = (t >= off) ? start[t - off] : 0;
        __syncthreads();
        start[t] += u;
        __syncthreads();
    }
    int excl = start[t] - v;
    start[t] = excl;
    cur[t] = excl;
    __syncthreads();
    #pragma unroll
    for (int i = 0; i < EPB / 256; ++i) {
        int b = (int)((ent[i] & 0xffffu) >> 8);
        int slot = atomicAdd(&cur[b], 1);
        stage[slot] = ent[i];
    }
    __syncthreads();
    int s0 = t * (EPB / 256);
    #pragma unroll
    for (int i = 0; i < EPB / 256; ++i) {
        unsigned int p = stage[s0 + i];
        int b = (int)((p & 0xffffu) >> 8);
        edge_part[gcur[b] + (s0 + i - start[b])] = p;
    }
}

__global__ __launch_bounds__(256) void finalize_kernel(const unsigned int* __restrict__ edge_part,
                                                       const int* __restrict__ cursor_mat,
                                                       int* __restrict__ row_ptr,
                                                       int* __restrict__ csr_src) {
    __shared__ int h[256];
    __shared__ int sc[256];
    __shared__ int cur[256];
    __shared__ unsigned short stage[K4CAP];
    int t = threadIdx.x;
    int b = blockIdx.x;
    int cs = cursor_mat[b * PBLOCKS];
    int ce = (b == NBUCK - 1) ? N_EDGES : cursor_mat[(b + 1) * PBLOCKS];
    int cnt = ce - cs;
    h[t] = 0;
    __syncthreads();
    for (int i = t; i < cnt; i += 256)
        atomicAdd(&h[edge_part[cs + i] & 0xffu], 1);
    __syncthreads();
    int v = h[t];
    sc[t] = v;
    __syncthreads();
    for (int off = 1; off < 256; off <<= 1) {
        int u = (t >= off) ? sc[t - off] : 0;
        __syncthreads();
        sc[t] += u;
        __syncthreads();
    }
    int excl = sc[t] - v;
    row_ptr[b * 256 + t] = cs + excl;
    cur[t] = excl;
    __syncthreads();
    if (cnt <= K4CAP) {
        for (int i = t; i < cnt; i += 256) {
            unsigned int p = edge_part[cs + i];
            int slot = atomicAdd(&cur[p & 0xffu], 1);
            stage[slot] = (unsigned short)(p >> 16);
        }
        __syncthreads();
        for (int i = t; i < cnt; i += 256)
            csr_src[cs + i] = (int)stage[i];
    } else {
        for (int i = t; i < cnt; i += 256) {
            unsigned int p = edge_part[cs + i];
            int slot = atomicAdd(&cur[p & 0xffu], 1);
            csr_src[cs + slot] = (int)(p >> 16);
        }
    }
}

// ---------------- GEMM via MFMA 16x16x32 bf16 (fp32 accum, bf16 out) ----------------
// block = 256 thr = 4 waves = 64 nodes; W pre-swizzled in LDS to B-frag layout.
// A: lane holds A[m=lane&15][k=quad*8+j]; C/D: col=lane&15, row=quad*4+reg.

template <int OUTC>
__global__ __launch_bounds__(256) void gemm_mfma(const float* __restrict__ X,
                                                 const float* __restrict__ W,
                                                 unsigned short* __restrict__ H) {
    constexpr int NT = OUTC / 16;          // 16-wide col tiles
    extern __shared__ unsigned short Wl[]; // [NT*4][64][8] bf16 frag-ordered
    int t = threadIdx.x;
    for (int idx = t; idx < OUTC * 128; idx += 256) {
        int j = idx & 7;
        int ln = (idx >> 3) & 63;
        int fc = idx >> 9;                 // frag = ct*4 + kc
        int kc = fc & 3, ct = fc >> 2;
        int k = kc * 32 + (ln >> 4) * 8 + j;
        int n = ct * 16 + (ln & 15);
        Wl[idx] = (unsigned short)f2bf(W[k * OUTC + n]);
    }
    __syncthreads();
    int wave = t >> 6, lane = t & 63;
    int m = lane & 15, quad = lane >> 4;
    int node_base = blockIdx.x * 64 + wave * 16;
    const float* xrow = X + (size_t)(node_base + m) * 128 + quad * 8;
    bf16x8 a[4];
    #pragma unroll
    for (int kc = 0; kc < 4; ++kc) {
        float4 u = *(const float4*)(xrow + kc * 32);
        float4 v = *(const float4*)(xrow + kc * 32 + 4);
        bf16x8 af;
        af[0] = (short)f2bf(u.x); af[1] = (short)f2bf(u.y);
        af[2] = (short)f2bf(u.z); af[3] = (short)f2bf(u.w);
        af[4] = (short)f2bf(v.x); af[5] = (short)f2bf(v.y);
        af[6] = (short)f2bf(v.z); af[7] = (short)f2bf(v.w);
        a[kc] = af;
    }
    #pragma unroll
    for (int ct = 0; ct < NT; ++ct) {
        f32x4 acc = {0.f, 0.f, 0.f, 0.f};
        #pragma unroll
        for (int kc = 0; kc < 4; ++kc) {
            bf16x8 bfr = *(const bf16x8*)(Wl + ((ct * 4 + kc) * 64 + lane) * 8);
            acc = __builtin_amdgcn_mfma_f32_16x16x32_bf16(a[kc], bfr, acc, 0, 0, 0);
        }
        #pragma unroll
        for (int r = 0; r < 4; ++r) {
            int row = quad * 4 + r;
            H[(size_t)(node_base + row) * OUTC + ct * 16 + m] = (unsigned short)f2bf(acc[r]);
        }
    }
}

// ---------------- attention logits (bf16 h) ----------------

__global__ __launch_bounds__(256) void att1_kernel(const unsigned int* __restrict__ h1u,
                                                   const float* __restrict__ as_w,
                                                   const float* __restrict__ ad_w,
                                                   float* __restrict__ a_src,
                                                   float* __restrict__ a_dst) {
    int wave = (blockIdx.x * 256 + threadIdx.x) >> 6;
    int lane = threadIdx.x & 63;
    unsigned int p = h1u[wave * 64 + lane];
    float h0 = bflo(p), h1v = bfhi(p);
    float2 sw = *(const float2*)(as_w + lane * 2);
    float2 dw = *(const float2*)(ad_w + lane * 2);
    float ps = h0 * sw.x + h1v * sw.y;
    float pd = h0 * dw.x + h1v * dw.y;
    #pragma unroll
    for (int m = 1; m < 16; m <<= 1) {
        ps += __shfl_xor(ps, m);
        pd += __shfl_xor(pd, m);
    }
    if ((lane & 15) == 0) {
        a_src[wave * 4 + (lane >> 4)] = ps;
        a_dst[wave * 4 + (lane >> 4)] = pd;
    }
}

__global__ __launch_bounds__(256) void att2_kernel(const unsigned short* __restrict__ h2u,
                                                   const float* __restrict__ as_w,
                                                   const float* __restrict__ ad_w,
                                                   float* __restrict__ a_src,
                                                   float* __restrict__ a_dst) {
    int wave = (blockIdx.x * 256 + threadIdx.x) >> 6;
    int lane = threadIdx.x & 63;
    float v = bf2f(h2u[wave * 64 + lane]);
    float ps = v * as_w[lane];
    float pd = v * ad_w[lane];
    #pragma unroll
    for (int m = 1; m < 64; m <<= 1) {
        ps += __shfl_xor(ps, m);
        pd += __shfl_xor(pd, m);
    }
    if (lane == 0) {
        a_src[wave] = ps;
        a_dst[wave] = pd;
    }
}

// ---------------- edge aggregation (softmax fused, 16-edge batches, predicated tail) ----
// mean degree = 16, so batch = 16 edges, fully unrolled (16 gathers in flight);
// tail is ONE predicated unrolled batch (w=0 for j>=mb), never a serial loop.

__global__ __launch_bounds__(256) void agg1_kernel(const int* __restrict__ row_ptr,
                                                   const int* __restrict__ csr_src,
                                                   const unsigned int* __restrict__ h1u,
                                                   const float* __restrict__ a_src,
                                                   const float* __restrict__ a_dst,
                                                   const float* __restrict__ b1,
                                                   float* __restrict__ x2) {
    int n = (blockIdx.x * 256 + threadIdx.x) >> 6;
    int lane = threadIdx.x & 63;
    int hd = lane >> 4;
    int j16 = lane & 15;
    int wbase = lane & 48;
    int c0 = lane * 2;
    float ad = a_dst[n * 4 + hd];
    int e = row_ptr[n], end = row_ptr[n + 1];
    float acc0 = 0.f, acc1 = 0.f, denom = 0.f;
    while (e + 16 <= end) {
        int s_l = csr_src[e + j16];                        // edge j16's src (quads redundant)
        float wv = lrelu_exp(a_src[s_l * 4 + hd] + ad);    // w(edge j16, head hd)
        #pragma unroll
        for (int j = 0; j < 16; ++j) {
            int s = __shfl(s_l, j);
            float w = __shfl(wv, wbase + j);
            unsigned int p = h1u[(size_t)s * 64 + lane];
            denom += w;
            acc0 += w * bflo(p);
            acc1 += w * bfhi(p);
        }
        e += 16;
    }
    if (e < end) {
        int mb = end - e;
        int s_l = csr_src[e + (j16 < mb ? j16 : 0)];
        float wv = lrelu_exp(a_src[s_l * 4 + hd] + ad);
        #pragma unroll
        for (int j = 0; j < 16; ++j) {
            int s = __shfl(s_l, j);
            float w = (j < mb) ? __shfl(wv, wbase + j) : 0.f;
            unsigned int p = h1u[(size_t)s * 64 + lane];
            denom += w;
            acc0 += w * bflo(p);
            acc1 += w * bfhi(p);
        }
    }
    float inv = 1.f / (denom + EPS_);
    float o0 = acc0 * inv + b1[c0];
    float o1 = acc1 * inv + b1[c0 + 1];
    o0 = 1.f / (1.f + __expf(-o0));
    o1 = 1.f / (1.f + __expf(-o1));
    *(float2*)(x2 + (size_t)n * 128 + c0) = make_float2(o0, o1);
}

__global__ __launch_bounds__(256) void agg2_kernel(const int* __restrict__ row_ptr,
                                                   const int* __restrict__ csr_src,
                                                   const unsigned short* __restrict__ h2u,
                                                   const float* __restrict__ a_src,
                                                   const float* __restrict__ a_dst,
                                                   const float* __restrict__ b2,
                                                   float* __restrict__ out) {
    int n = (blockIdx.x * 256 + threadIdx.x) >> 6;
    int lane = threadIdx.x & 63;
    int j16 = lane & 15;
    float ad = a_dst[n];
    int e = row_ptr[n], end = row_ptr[n + 1];
    float acc = 0.f, denom = 0.f;
    while (e + 16 <= end) {
        int s_l = csr_src[e + j16];                        // lanes 16.. redundant (broadcast)
        float wv = lrelu_exp(a_src[s_l] + ad);
        #pragma unroll
        for (int j = 0; j < 16; ++j) {
            int s = __shfl(s_l, j);
            float w = __shfl(wv, j);
            denom += w;
            acc += w * bf2f(h2u[(size_t)s * 64 + lane]);
        }
        e += 16;
    }
    if (e < end) {
        int mb = end - e;
        int s_l = csr_src[e + (j16 < mb ? j16 : 0)];
        float wv = lrelu_exp(a_src[s_l] + ad);
        #pragma unroll
        for (int j = 0; j < 16; ++j) {
            int s = __shfl(s_l, j);
            float w = (j < mb) ? __shfl(wv, j) : 0.f;
            denom += w;
            acc += w * bf2f(h2u[(size_t)s * 64 + lane]);
        }
    }
    float o = acc / (denom + EPS_) + b2[lane];
    out[(size_t)n * 64 + lane] = 1.f / (1.f + __expf(-o));
}

// ---------------- launch ----------------

extern "C" void kernel_launch(void* const* d_in, const int* in_sizes, int n_in,
                              void* d_out, int out_size, void* d_ws, size_t ws_size,
                              hipStream_t stream) {
    (void)in_sizes; (void)n_in; (void)out_size; (void)ws_size;
    const float* x   = (const float*)d_in[0];
    const int*   ei  = (const int*)d_in[1];
    const float* W1  = (const float*)d_in[2];
    const float* as1 = (const float*)d_in[3];
    const float* ad1 = (const float*)d_in[4];
    const float* b1  = (const float*)d_in[5];
    const float* W2  = (const float*)d_in[6];
    const float* as2 = (const float*)d_in[7];
    const float* ad2 = (const float*)d_in[8];
    const float* b2  = (const float*)d_in[9];
    float* out = (float*)d_out;

    char* p = (char*)d_ws;
    auto alloc = [&](size_t bytes) -> void* {
        void* r = (void*)p;
        p += (bytes + 255) & ~(size_t)255;
        return r;
    };
    int* hist_mat   = (int*)alloc((size_t)NBUCK * PBLOCKS * 4);
    int* cursor_mat = (int*)alloc((size_t)NBUCK * PBLOCKS * 4);
    int* bsum       = (int*)alloc(64 * 4);
    unsigned int* edge_part = (unsigned int*)alloc((size_t)N_EDGES * 4);
    int* row_ptr    = (int*)alloc((size_t)(N_NODES + 1) * 4);
    int* csr_src    = (int*)alloc((size_t)N_EDGES * 4);
    unsigned short* h1 = (unsigned short*)alloc((size_t)N_NODES * 128 * 2);
    float* a_src1   = (float*)alloc((size_t)N_NODES * 4 * 4);
    float* a_dst1   = (float*)alloc((size_t)N_NODES * 4 * 4);
    float* x2       = (float*)alloc((size_t)N_NODES * 128 * 4);
    unsigned short* h2 = (unsigned short*)alloc((size_t)N_NODES * 64 * 2);
    float* a_src2   = (float*)alloc((size_t)N_NODES * 4);
    float* a_dst2   = (float*)alloc((size_t)N_NODES * 4);

    // CSR build (atomic-free radix partition)
    coarse_hist<<<PBLOCKS, 256, 0, stream>>>(ei, hist_mat);
    scan_a<<<64, 1024, 0, stream>>>(hist_mat, cursor_mat, bsum);
    scan_b<<<1, 64, 0, stream>>>(bsum, row_ptr);
    scan_c<<<64, 1024, 0, stream>>>(cursor_mat, bsum);
    partition_kernel<<<PBLOCKS, 256, 0, stream>>>(ei, cursor_mat, edge_part);
    finalize_kernel<<<NBUCK, 256, 0, stream>>>(edge_part, cursor_mat, row_ptr, csr_src);

    // layer 1
    gemm_mfma<128><<<N_NODES / 64, 256, 128 * 128 * 2, stream>>>(x, W1, h1);
    att1_kernel<<<N_NODES / 4, 256, 0, stream>>>((const unsigned int*)h1, as1, ad1, a_src1, a_dst1);
    agg1_kernel<<<N_NODES / 4, 256, 0, stream>>>(row_ptr, csr_src, (const unsigned int*)h1,
                                                 a_src1, a_dst1, b1, x2);

    // layer 2
    gemm_mfma<64><<<N_NODES / 64, 256, 128 * 64 * 2, stream>>>(x2, W2, h2);
    att2_kernel<<<N_NODES / 4, 256, 0, stream>>>(h2, as2, ad2, a_src2, a_dst2);
    agg2_kernel<<<N_NODES / 4, 256, 0, stream>>>(row_ptr, csr_src, h2, a_src2, a_dst2, b2, out);
}

// Round 10
// 262.840 us; speedup vs baseline: 1.4333x; 1.0432x over previous
//
#include <hip/hip_runtime.h>

#define N_NODES 65536
#define N_EDGES 1048576
#define NBUCK 256                 // coarse buckets (dst>>8), 256 nodes each
#define PBLOCKS 256               // partition blocks
#define EPB (N_EDGES / PBLOCKS)   // 4096 edges per partition block
#define K4CAP 6144                // finalize LDS staging capacity (mean 4096, sigma 64)
constexpr float NEG = 0.2f;
constexpr float EPS_ = 1e-16f;

typedef __attribute__((ext_vector_type(8))) short bf16x8;
typedef __attribute__((ext_vector_type(4))) float f32x4;

// bf16 helpers (bit tricks; no NaN inputs here)
__device__ __forceinline__ unsigned short f2bf(float f) {
    unsigned int u = __float_as_uint(f);
    return (unsigned short)((u + 0x7fffu + ((u >> 16) & 1u)) >> 16);
}
__device__ __forceinline__ float bflo(unsigned int p) { return __uint_as_float(p << 16); }
__device__ __forceinline__ float bfhi(unsigned int p) { return __uint_as_float(p & 0xffff0000u); }
__device__ __forceinline__ float bf2f(unsigned short u) { return __uint_as_float((unsigned int)u << 16); }
__device__ __forceinline__ float lrelu_exp(float l) { return __expf(fmaxf(l, NEG * l)); }

// ---------------- CSR build: radix partition by dst>>8, no global atomics ----------------

__global__ __launch_bounds__(256) void coarse_hist(const int* __restrict__ ei,
                                                   int* __restrict__ hist_mat) {
    __shared__ int h[NBUCK];
    int t = threadIdx.x;
    h[t] = 0;
    __syncthreads();
    int base = blockIdx.x * EPB;
    #pragma unroll
    for (int i = 0; i < EPB / 256; ++i) {
        int d = ei[N_EDGES + base + i * 256 + t];
        atomicAdd(&h[d >> 8], 1);
    }
    __syncthreads();
    hist_mat[t * PBLOCKS + blockIdx.x] = h[t];
}

__global__ __launch_bounds__(1024) void scan_a(const int* __restrict__ in,
                                               int* __restrict__ out,
                                               int* __restrict__ bsum) {
    __shared__ int sm[1024];
    int t = threadIdx.x, i = blockIdx.x * 1024 + t;
    int v = in[i];
    sm[t] = v;
    __syncthreads();
    for (int off = 1; off < 1024; off <<= 1) {
        int u = (t >= off) ? sm[t - off] : 0;
        __syncthreads();
        sm[t] += u;
        __syncthreads();
    }
    out[i] = sm[t] - v;
    if (t == 1023) bsum[blockIdx.x] = sm[t];
}

// scan_c now also folds the 64-entry block-offset scan (was scan_b)
__global__ __launch_bounds__(1024) void scan_c(int* __restrict__ arr,
                                               const int* __restrict__ bsum) {
    __shared__ int off[64];
    int t = threadIdx.x;
    if (t < 64) {
        int v = bsum[t];
        int incl = v;
        #pragma unroll
        for (int o = 1; o < 64; o <<= 1) {
            int u = __shfl_up(incl, o);
            if (t >= o) incl += u;
        }
        off[t] = incl - v;
    }
    __syncthreads();
    int i = blockIdx.x * 1024 + t;
    arr[i] += off[blockIdx.x];
}

__global__ __launch_bounds__(256) void partition_kernel(const int* __restrict__ ei,
                                                        const int* __restrict__ cursor_mat,
                                                        unsigned int* __restrict__ edge_part) {
    __shared__ int h[NBUCK];
    __shared__ int start[NBUCK];
    __shared__ int cur[NBUCK];
    __shared__ int gcur[NBUCK];
    __shared__ unsigned int stage[EPB];
    int t = threadIdx.x;
    h[t] = 0;
    gcur[t] = cursor_mat[t * PBLOCKS + blockIdx.x];
    __syncthreads();
    unsigned int ent[EPB / 256];
    int base = blockIdx.x * EPB;
    #pragma unroll
    for (int i = 0; i < EPB / 256; ++i) {
        int e = base + i * 256 + t;
        int s = ei[e], d = ei[N_EDGES + e];
        ent[i] = ((unsigned int)s << 16) | (unsigned int)d;   // src,dst both < 2^16
        atomicAdd(&h[d >> 8], 1);
    }
    __syncthreads();
    int v = h[t];
    start[t] = v;
    __syncthreads();
    for (int off = 1; off < 256; off <<= 1) {
        int u = (t >= off) ? start[t - off] : 0;
        __syncthreads();
        start[t] += u;
        __syncthreads();
    }
    int excl = start[t] - v;
    start[t] = excl;
    cur[t] = excl;
    __syncthreads();
    #pragma unroll
    for (int i = 0; i < EPB / 256; ++i) {
        int b = (int)((ent[i] & 0xffffu) >> 8);
        int slot = atomicAdd(&cur[b], 1);
        stage[slot] = ent[i];
    }
    __syncthreads();
    int s0 = t * (EPB / 256);
    #pragma unroll
    for (int i = 0; i < EPB / 256; ++i) {
        unsigned int p = stage[s0 + i];
        int b = (int)((p & 0xffffu) >> 8);
        edge_part[gcur[b] + (s0 + i - start[b])] = p;
    }
}

__global__ __launch_bounds__(256) void finalize_kernel(const unsigned int* __restrict__ edge_part,
                                                       const int* __restrict__ cursor_mat,
                                                       int* __restrict__ row_ptr,
                                                       int* __restrict__ csr_src) {
    __shared__ int h[256];
    __shared__ int sc[256];
    __shared__ int cur[256];
    __shared__ unsigned short stage[K4CAP];
    int t = threadIdx.x;
    int b = blockIdx.x;
    if (b == NBUCK - 1 && t == 0) row_ptr[N_NODES] = N_EDGES;
    int cs = cursor_mat[b * PBLOCKS];
    int ce = (b == NBUCK - 1) ? N_EDGES : cursor_mat[(b + 1) * PBLOCKS];
    int cnt = ce - cs;
    h[t] = 0;
    __syncthreads();
    for (int i = t; i < cnt; i += 256)
        atomicAdd(&h[edge_part[cs + i] & 0xffu], 1);
    __syncthreads();
    int v = h[t];
    sc[t] = v;
    __syncthreads();
    for (int off = 1; off < 256; off <<= 1) {
        int u = (t >= off) ? sc[t - off] : 0;
        __syncthreads();
        sc[t] += u;
        __syncthreads();
    }
    int excl = sc[t] - v;
    row_ptr[b * 256 + t] = cs + excl;
    cur[t] = excl;
    __syncthreads();
    if (cnt <= K4CAP) {
        for (int i = t; i < cnt; i += 256) {
            unsigned int p = edge_part[cs + i];
            int slot = atomicAdd(&cur[p & 0xffu], 1);
            stage[slot] = (unsigned short)(p >> 16);
        }
        __syncthreads();
        for (int i = t; i < cnt; i += 256)
            csr_src[cs + i] = (int)stage[i];
    } else {
        for (int i = t; i < cnt; i += 256) {
            unsigned int p = edge_part[cs + i];
            int slot = atomicAdd(&cur[p & 0xffu], 1);
            csr_src[cs + slot] = (int)(p >> 16);
        }
    }
}

// ---------------- GEMM via MFMA 16x16x32 bf16 (fp32 accum, bf16 out) ----------------

template <int OUTC>
__global__ __launch_bounds__(256) void gemm_mfma(const float* __restrict__ X,
                                                 const float* __restrict__ W,
                                                 unsigned short* __restrict__ H) {
    constexpr int NT = OUTC / 16;          // 16-wide col tiles
    extern __shared__ unsigned short Wl[]; // [NT*4][64][8] bf16 frag-ordered
    int t = threadIdx.x;
    for (int idx = t; idx < OUTC * 128; idx += 256) {
        int j = idx & 7;
        int ln = (idx >> 3) & 63;
        int fc = idx >> 9;                 // frag = ct*4 + kc
        int kc = fc & 3, ct = fc >> 2;
        int k = kc * 32 + (ln >> 4) * 8 + j;
        int n = ct * 16 + (ln & 15);
        Wl[idx] = (unsigned short)f2bf(W[k * OUTC + n]);
    }
    __syncthreads();
    int wave = t >> 6, lane = t & 63;
    int m = lane & 15, quad = lane >> 4;
    int node_base = blockIdx.x * 64 + wave * 16;
    const float* xrow = X + (size_t)(node_base + m) * 128 + quad * 8;
    bf16x8 a[4];
    #pragma unroll
    for (int kc = 0; kc < 4; ++kc) {
        float4 u = *(const float4*)(xrow + kc * 32);
        float4 v = *(const float4*)(xrow + kc * 32 + 4);
        bf16x8 af;
        af[0] = (short)f2bf(u.x); af[1] = (short)f2bf(u.y);
        af[2] = (short)f2bf(u.z); af[3] = (short)f2bf(u.w);
        af[4] = (short)f2bf(v.x); af[5] = (short)f2bf(v.y);
        af[6] = (short)f2bf(v.z); af[7] = (short)f2bf(v.w);
        a[kc] = af;
    }
    #pragma unroll
    for (int ct = 0; ct < NT; ++ct) {
        f32x4 acc = {0.f, 0.f, 0.f, 0.f};
        #pragma unroll
        for (int kc = 0; kc < 4; ++kc) {
            bf16x8 bfr = *(const bf16x8*)(Wl + ((ct * 4 + kc) * 64 + lane) * 8);
            acc = __builtin_amdgcn_mfma_f32_16x16x32_bf16(a[kc], bfr, acc, 0, 0, 0);
        }
        #pragma unroll
        for (int r = 0; r < 4; ++r) {
            int row = quad * 4 + r;
            H[(size_t)(node_base + row) * OUTC + ct * 16 + m] = (unsigned short)f2bf(acc[r]);
        }
    }
}

// ---------------- attention logits (bf16 h) ----------------

__global__ __launch_bounds__(256) void att1_kernel(const unsigned int* __restrict__ h1u,
                                                   const float* __restrict__ as_w,
                                                   const float* __restrict__ ad_w,
                                                   float* __restrict__ a_src,
                                                   float* __restrict__ a_dst) {
    int wave = (blockIdx.x * 256 + threadIdx.x) >> 6;
    int lane = threadIdx.x & 63;
    unsigned int p = h1u[wave * 64 + lane];
    float h0 = bflo(p), h1v = bfhi(p);
    float2 sw = *(const float2*)(as_w + lane * 2);
    float2 dw = *(const float2*)(ad_w + lane * 2);
    float ps = h0 * sw.x + h1v * sw.y;
    float pd = h0 * dw.x + h1v * dw.y;
    #pragma unroll
    for (int m = 1; m < 16; m <<= 1) {
        ps += __shfl_xor(ps, m);
        pd += __shfl_xor(pd, m);
    }
    if ((lane & 15) == 0) {
        a_src[wave * 4 + (lane >> 4)] = ps;
        a_dst[wave * 4 + (lane >> 4)] = pd;
    }
}

__global__ __launch_bounds__(256) void att2_kernel(const unsigned short* __restrict__ h2u,
                                                   const float* __restrict__ as_w,
                                                   const float* __restrict__ ad_w,
                                                   float* __restrict__ a_src,
                                                   float* __restrict__ a_dst) {
    int wave = (blockIdx.x * 256 + threadIdx.x) >> 6;
    int lane = threadIdx.x & 63;
    float v = bf2f(h2u[wave * 64 + lane]);
    float ps = v * as_w[lane];
    float pd = v * ad_w[lane];
    #pragma unroll
    for (int m = 1; m < 64; m <<= 1) {
        ps += __shfl_xor(ps, m);
        pd += __shfl_xor(pd, m);
    }
    if (lane == 0) {
        a_src[wave] = ps;
        a_dst[wave] = pd;
    }
}

// ---------------- edge aggregation: quad-per-edge uint4 gather, packed (w,s) ----------
// agg1: wave per dst node. Per 16-edge batch: lane (hd=lane>>4, j16=lane&15) computes
// w(edge j16, head hd) once, packs (bf16(w)<<16)|s. Inner: per g, each quad handles
// edge g*4+quad; lane loads uint4 = 8 bf16 channels (col=lane&15 -> ch col*8..+7).
// One bpermute per lane per 4 edges. Cross-quad xor-reduce at the end.

__global__ __launch_bounds__(256) void agg1_kernel(const int* __restrict__ row_ptr,
                                                   const int* __restrict__ csr_src,
                                                   const unsigned int* __restrict__ h1u,
                                                   const float* __restrict__ a_src,
                                                   const float* __restrict__ a_dst,
                                                   const float* __restrict__ b1,
                                                   float* __restrict__ x2) {
    int n = (blockIdx.x * 256 + threadIdx.x) >> 6;
    int lane = threadIdx.x & 63;
    int quad = lane >> 4;          // edge-slot role
    int col = lane & 15;           // channel-group role: channels col*8..col*8+7
    int j16 = lane & 15;           // batch-load role
    int hd_w = lane >> 4;          // head for w computation
    int hd_c = col >> 2;           // head of this lane's channels
    float adw = a_dst[n * 4 + hd_w];
    int e = row_ptr[n], end = row_ptr[n + 1];
    float acc[8] = {};
    float denom = 0.f;
    while (e < end) {
        int mb = end - e;
        if (mb > 16) mb = 16;
        int s_l = csr_src[e + (j16 < mb ? j16 : 0)];
        float wv = lrelu_exp(a_src[s_l * 4 + hd_w] + adw);
        unsigned int pack = ((unsigned int)f2bf(wv) << 16) | (unsigned int)s_l;
        #pragma unroll
        for (int g = 0; g < 4; ++g) {
            int j = g * 4 + quad;
            unsigned int pk = __shfl(pack, hd_c * 16 + j);
            float w = (j < mb) ? __uint_as_float(pk & 0xffff0000u) : 0.f;
            unsigned int s = pk & 0xffffu;
            uint4 hv = *(const uint4*)(h1u + s * 64 + col * 4);
            denom += w;
            acc[0] += w * bflo(hv.x); acc[1] += w * bfhi(hv.x);
            acc[2] += w * bflo(hv.y); acc[3] += w * bfhi(hv.y);
            acc[4] += w * bflo(hv.z); acc[5] += w * bfhi(hv.z);
            acc[6] += w * bflo(hv.w); acc[7] += w * bfhi(hv.w);
        }
        e += 16;
    }
    #pragma unroll
    for (int m = 16; m < 64; m <<= 1) {
        denom += __shfl_xor(denom, m);
        #pragma unroll
        for (int i = 0; i < 8; ++i) acc[i] += __shfl_xor(acc[i], m);
    }
    if (quad == 0) {
        float inv = 1.f / (denom + EPS_);
        int c0 = col * 8;
        float o[8];
        #pragma unroll
        for (int i = 0; i < 8; ++i) {
            float v = acc[i] * inv + b1[c0 + i];
            o[i] = 1.f / (1.f + __expf(-v));
        }
        float4* dst = (float4*)(x2 + (size_t)n * 128 + c0);
        dst[0] = make_float4(o[0], o[1], o[2], o[3]);
        dst[1] = make_float4(o[4], o[5], o[6], o[7]);
    }
}

// agg2: 8-lane groups, 8 edges per uint4 load round. h2 row = 32 uints.

__global__ __launch_bounds__(256) void agg2_kernel(const int* __restrict__ row_ptr,
                                                   const int* __restrict__ csr_src,
                                                   const unsigned int* __restrict__ h2u,
                                                   const float* __restrict__ a_src,
                                                   const float* __restrict__ a_dst,
                                                   const float* __restrict__ b2,
                                                   float* __restrict__ out) {
    int n = (blockIdx.x * 256 + threadIdx.x) >> 6;
    int lane = threadIdx.x & 63;
    int grp = lane >> 3;           // edge-slot role (8 slots)
    int col = lane & 7;            // channels col*8..col*8+7
    int j16 = lane & 15;
    float ad = a_dst[n];
    int e = row_ptr[n], end = row_ptr[n + 1];
    float acc[8] = {};
    float denom = 0.f;
    while (e < end) {
        int mb = end - e;
        if (mb > 16) mb = 16;
        int s_l = csr_src[e + (j16 < mb ? j16 : 0)];
        float wv = lrelu_exp(a_src[s_l] + ad);
        unsigned int pack = ((unsigned int)f2bf(wv) << 16) | (unsigned int)s_l;
        #pragma unroll
        for (int g = 0; g < 2; ++g) {
            int j = g * 8 + grp;
            unsigned int pk = __shfl(pack, j);     // lanes 0..15 hold batch packs
            float w = (j < mb) ? __uint_as_float(pk & 0xffff0000u) : 0.f;
            unsigned int s = pk & 0xffffu;
            uint4 hv = *(const uint4*)(h2u + s * 32 + col * 4);
            denom += w;
            acc[0] += w * bflo(hv.x); acc[1] += w * bfhi(hv.x);
            acc[2] += w * bflo(hv.y); acc[3] += w * bfhi(hv.y);
            acc[4] += w * bflo(hv.z); acc[5] += w * bfhi(hv.z);
            acc[6] += w * bflo(hv.w); acc[7] += w * bfhi(hv.w);
        }
        e += 16;
    }
    #pragma unroll
    for (int m = 8; m < 64; m <<= 1) {
        denom += __shfl_xor(denom, m);
        #pragma unroll
        for (int i = 0; i < 8; ++i) acc[i] += __shfl_xor(acc[i], m);
    }
    if (lane < 8) {
        float inv = 1.f / (denom + EPS_);
        int c0 = col * 8;
        float o[8];
        #pragma unroll
        for (int i = 0; i < 8; ++i) {
            float v = acc[i] * inv + b2[c0 + i];
            o[i] = 1.f / (1.f + __expf(-v));
        }
        float4* dst = (float4*)(out + (size_t)n * 64 + c0);
        dst[0] = make_float4(o[0], o[1], o[2], o[3]);
        dst[1] = make_float4(o[4], o[5], o[6], o[7]);
    }
}

// ---------------- launch ----------------

extern "C" void kernel_launch(void* const* d_in, const int* in_sizes, int n_in,
                              void* d_out, int out_size, void* d_ws, size_t ws_size,
                              hipStream_t stream) {
    (void)in_sizes; (void)n_in; (void)out_size; (void)ws_size;
    const float* x   = (const float*)d_in[0];
    const int*   ei  = (const int*)d_in[1];
    const float* W1  = (const float*)d_in[2];
    const float* as1 = (const float*)d_in[3];
    const float* ad1 = (const float*)d_in[4];
    const float* b1  = (const float*)d_in[5];
    const float* W2  = (const float*)d_in[6];
    const float* as2 = (const float*)d_in[7];
    const float* ad2 = (const float*)d_in[8];
    const float* b2  = (const float*)d_in[9];
    float* out = (float*)d_out;

    char* p = (char*)d_ws;
    auto alloc = [&](size_t bytes) -> void* {
        void* r = (void*)p;
        p += (bytes + 255) & ~(size_t)255;
        return r;
    };
    int* hist_mat   = (int*)alloc((size_t)NBUCK * PBLOCKS * 4);
    int* cursor_mat = (int*)alloc((size_t)NBUCK * PBLOCKS * 4);
    int* bsum       = (int*)alloc(64 * 4);
    unsigned int* edge_part = (unsigned int*)alloc((size_t)N_EDGES * 4);
    int* row_ptr    = (int*)alloc((size_t)(N_NODES + 1) * 4);
    int* csr_src    = (int*)alloc((size_t)N_EDGES * 4);
    unsigned short* h1 = (unsigned short*)alloc((size_t)N_NODES * 128 * 2);
    float* a_src1   = (float*)alloc((size_t)N_NODES * 4 * 4);
    float* a_dst1   = (float*)alloc((size_t)N_NODES * 4 * 4);
    float* x2       = (float*)alloc((size_t)N_NODES * 128 * 4);
    unsigned short* h2 = (unsigned short*)alloc((size_t)N_NODES * 64 * 2);
    float* a_src2   = (float*)alloc((size_t)N_NODES * 4);
    float* a_dst2   = (float*)alloc((size_t)N_NODES * 4);

    // CSR build (atomic-free radix partition)
    coarse_hist<<<PBLOCKS, 256, 0, stream>>>(ei, hist_mat);
    scan_a<<<64, 1024, 0, stream>>>(hist_mat, cursor_mat, bsum);
    scan_c<<<64, 1024, 0, stream>>>(cursor_mat, bsum);
    partition_kernel<<<PBLOCKS, 256, 0, stream>>>(ei, cursor_mat, edge_part);
    finalize_kernel<<<NBUCK, 256, 0, stream>>>(edge_part, cursor_mat, row_ptr, csr_src);

    // layer 1
    gemm_mfma<128><<<N_NODES / 64, 256, 128 * 128 * 2, stream>>>(x, W1, h1);
    att1_kernel<<<N_NODES / 4, 256, 0, stream>>>((const unsigned int*)h1, as1, ad1, a_src1, a_dst1);
    agg1_kernel<<<N_NODES / 4, 256, 0, stream>>>(row_ptr, csr_src, (const unsigned int*)h1,
                                                 a_src1, a_dst1, b1, x2);

    // layer 2
    gemm_mfma<64><<<N_NODES / 64, 256, 128 * 64 * 2, stream>>>(x2, W2, h2);
    att2_kernel<<<N_NODES / 4, 256, 0, stream>>>(h2, as2, ad2, a_src2, a_dst2);
    agg2_kernel<<<N_NODES / 4, 256, 0, stream>>>(row_ptr, csr_src, (const unsigned int*)h2,
                                                 a_src2, a_dst2, b2, out);
}

// Round 12
// 258.430 us; speedup vs baseline: 1.4577x; 1.0171x over previous
//
#include <hip/hip_runtime.h>
#include <hip/hip_fp16.h>

#define N_NODES 65536
#define N_EDGES 1048576
#define NBUCK 256                 // coarse buckets (dst>>8), 256 nodes each
#define PBLOCKS 256               // partition blocks
#define EPB (N_EDGES / PBLOCKS)   // 4096 edges per partition block
#define K4CAP 6144                // finalize LDS staging capacity (mean 4096, sigma 64)
constexpr float NEG = 0.2f;
constexpr float EPS_ = 1e-16f;
constexpr float WSHIFT = 2.7725887f;   // ln(16): softmax-invariant shift, fp16 overflow guard

typedef __attribute__((ext_vector_type(8))) short bf16x8;
typedef __attribute__((ext_vector_type(4))) float f32x4;

// bf16 helpers (for MFMA fragments)
__device__ __forceinline__ unsigned short f2bf(float f) {
    unsigned int u = __float_as_uint(f);
    return (unsigned short)((u + 0x7fffu + ((u >> 16) & 1u)) >> 16);
}
// fp16 helpers
__device__ __forceinline__ unsigned short f2h(float f) {
    __half_raw r = __half_raw(__float2half(f));
    return r.x;
}
__device__ __forceinline__ __half2 u2h2(unsigned int u) {
    union { unsigned int u; __half2 h; } c; c.u = u; return c.h;
}
__device__ __forceinline__ unsigned int h22u(__half2 h) {
    union { unsigned int u; __half2 h; } c; c.h = h; return c.u;
}
__device__ __forceinline__ float lrelu_exp_s(float l) {
    return __expf(fmaxf(l, NEG * l) - WSHIFT);
}

// ---------------- CSR build: radix partition by dst>>8, no global atomics ----------------

__global__ __launch_bounds__(256) void coarse_hist(const int* __restrict__ ei,
                                                   int* __restrict__ hist_mat) {
    __shared__ int h[NBUCK];
    int t = threadIdx.x;
    h[t] = 0;
    __syncthreads();
    int base = blockIdx.x * EPB;
    #pragma unroll
    for (int i = 0; i < EPB / 256; ++i) {
        int d = ei[N_EDGES + base + i * 256 + t];
        atomicAdd(&h[d >> 8], 1);
    }
    __syncthreads();
    hist_mat[t * PBLOCKS + blockIdx.x] = h[t];
}

__global__ __launch_bounds__(1024) void scan_a(const int* __restrict__ in,
                                               int* __restrict__ out,
                                               int* __restrict__ bsum) {
    __shared__ int sm[1024];
    int t = threadIdx.x, i = blockIdx.x * 1024 + t;
    int v = in[i];
    sm[t] = v;
    __syncthreads();
    for (int off = 1; off < 1024; off <<= 1) {
        int u = (t >= off) ? sm[t - off] : 0;
        __syncthreads();
        sm[t] += u;
        __syncthreads();
    }
    out[i] = sm[t] - v;
    if (t == 1023) bsum[blockIdx.x] = sm[t];
}

__global__ __launch_bounds__(1024) void scan_c(int* __restrict__ arr,
                                               const int* __restrict__ bsum) {
    __shared__ int off[64];
    int t = threadIdx.x;
    if (t < 64) {
        int v = bsum[t];
        int incl = v;
        #pragma unroll
        for (int o = 1; o < 64; o <<= 1) {
            int u = __shfl_up(incl, o);
            if (t >= o) incl += u;
        }
        off[t] = incl - v;
    }
    __syncthreads();
    int i = blockIdx.x * 1024 + t;
    arr[i] += off[blockIdx.x];
}

__global__ __launch_bounds__(256) void partition_kernel(const int* __restrict__ ei,
                                                        const int* __restrict__ cursor_mat,
                                                        unsigned int* __restrict__ edge_part) {
    __shared__ int h[NBUCK];
    __shared__ int start[NBUCK];
    __shared__ int cur[NBUCK];
    __shared__ int gcur[NBUCK];
    __shared__ unsigned int stage[EPB];
    int t = threadIdx.x;
    h[t] = 0;
    gcur[t] = cursor_mat[t * PBLOCKS + blockIdx.x];
    __syncthreads();
    unsigned int ent[EPB / 256];
    int base = blockIdx.x * EPB;
    #pragma unroll
    for (int i = 0; i < EPB / 256; ++i) {
        int e = base + i * 256 + t;
        int s = ei[e], d = ei[N_EDGES + e];
        ent[i] = ((unsigned int)s << 16) | (unsigned int)d;   // src,dst both < 2^16
        atomicAdd(&h[d >> 8], 1);
    }
    __syncthreads();
    int v = h[t];
    start[t] = v;
    __syncthreads();
    for (int off = 1; off < 256; off <<= 1) {
        int u = (t >= off) ? start[t - off] : 0;
        __syncthreads();
        start[t] += u;
        __syncthreads();
    }
    int excl = start[t] - v;
    start[t] = excl;
    cur[t] = excl;
    __syncthreads();
    #pragma unroll
    for (int i = 0; i < EPB / 256; ++i) {
        int b = (int)((ent[i] & 0xffffu) >> 8);
        int slot = atomicAdd(&cur[b], 1);
        stage[slot] = ent[i];
    }
    __syncthreads();
    int s0 = t * (EPB / 256);
    #pragma unroll
    for (int i = 0; i < EPB / 256; ++i) {
        unsigned int p = stage[s0 + i];
        int b = (int)((p & 0xffffu) >> 8);
        edge_part[gcur[b] + (s0 + i - start[b])] = p;
    }
}

__global__ __launch_bounds__(256) void finalize_kernel(const unsigned int* __restrict__ edge_part,
                                                       const int* __restrict__ cursor_mat,
                                                       int* __restrict__ row_ptr,
                                                       int* __restrict__ csr_src) {
    __shared__ int h[256];
    __shared__ int sc[256];
    __shared__ int cur[256];
    __shared__ unsigned short stage[K4CAP];
    int t = threadIdx.x;
    int b = blockIdx.x;
    if (b == NBUCK - 1 && t == 0) row_ptr[N_NODES] = N_EDGES;
    int cs = cursor_mat[b * PBLOCKS];
    int ce = (b == NBUCK - 1) ? N_EDGES : cursor_mat[(b + 1) * PBLOCKS];
    int cnt = ce - cs;
    h[t] = 0;
    __syncthreads();
    for (int i = t; i < cnt; i += 256)
        atomicAdd(&h[edge_part[cs + i] & 0xffu], 1);
    __syncthreads();
    int v = h[t];
    sc[t] = v;
    __syncthreads();
    for (int off = 1; off < 256; off <<= 1) {
        int u = (t >= off) ? sc[t - off] : 0;
        __syncthreads();
        sc[t] += u;
        __syncthreads();
    }
    int excl = sc[t] - v;
    row_ptr[b * 256 + t] = cs + excl;
    cur[t] = excl;
    __syncthreads();
    if (cnt <= K4CAP) {
        for (int i = t; i < cnt; i += 256) {
            unsigned int p = edge_part[cs + i];
            int slot = atomicAdd(&cur[p & 0xffu], 1);
            stage[slot] = (unsigned short)(p >> 16);
        }
        __syncthreads();
        for (int i = t; i < cnt; i += 256)
            csr_src[cs + i] = (int)stage[i];
    } else {
        for (int i = t; i < cnt; i += 256) {
            unsigned int p = edge_part[cs + i];
            int slot = atomicAdd(&cur[p & 0xffu], 1);
            csr_src[cs + slot] = (int)(p >> 16);
        }
    }
}

// ---------------- GEMM via MFMA 16x16x32 bf16 (fp32 accum, fp16 out) ----------------

template <int OUTC>
__global__ __launch_bounds__(256) void gemm_mfma(const float* __restrict__ X,
                                                 const float* __restrict__ W,
                                                 unsigned short* __restrict__ H) {
    constexpr int NT = OUTC / 16;          // 16-wide col tiles
    extern __shared__ unsigned short Wl[]; // [NT*4][64][8] bf16 frag-ordered
    int t = threadIdx.x;
    for (int idx = t; idx < OUTC * 128; idx += 256) {
        int j = idx & 7;
        int ln = (idx >> 3) & 63;
        int fc = idx >> 9;                 // frag = ct*4 + kc
        int kc = fc & 3, ct = fc >> 2;
        int k = kc * 32 + (ln >> 4) * 8 + j;
        int n = ct * 16 + (ln & 15);
        Wl[idx] = (unsigned short)f2bf(W[k * OUTC + n]);
    }
    __syncthreads();
    int wave = t >> 6, lane = t & 63;
    int m = lane & 15, quad = lane >> 4;
    int node_base = blockIdx.x * 64 + wave * 16;
    const float* xrow = X + (size_t)(node_base + m) * 128 + quad * 8;
    bf16x8 a[4];
    #pragma unroll
    for (int kc = 0; kc < 4; ++kc) {
        float4 u = *(const float4*)(xrow + kc * 32);
        float4 v = *(const float4*)(xrow + kc * 32 + 4);
        bf16x8 af;
        af[0] = (short)f2bf(u.x); af[1] = (short)f2bf(u.y);
        af[2] = (short)f2bf(u.z); af[3] = (short)f2bf(u.w);
        af[4] = (short)f2bf(v.x); af[5] = (short)f2bf(v.y);
        af[6] = (short)f2bf(v.z); af[7] = (short)f2bf(v.w);
        a[kc] = af;
    }
    #pragma unroll
    for (int ct = 0; ct < NT; ++ct) {
        f32x4 acc = {0.f, 0.f, 0.f, 0.f};
        #pragma unroll
        for (int kc = 0; kc < 4; ++kc) {
            bf16x8 bfr = *(const bf16x8*)(Wl + ((ct * 4 + kc) * 64 + lane) * 8);
            acc = __builtin_amdgcn_mfma_f32_16x16x32_bf16(a[kc], bfr, acc, 0, 0, 0);
        }
        #pragma unroll
        for (int r = 0; r < 4; ++r) {
            int row = quad * 4 + r;
            H[(size_t)(node_base + row) * OUTC + ct * 16 + m] = f2h(acc[r]);
        }
    }
}

// ---------------- attention logits (fp16 h) ----------------

__global__ __launch_bounds__(256) void att1_kernel(const unsigned int* __restrict__ h1u,
                                                   const float* __restrict__ as_w,
                                                   const float* __restrict__ ad_w,
                                                   float* __restrict__ a_src,
                                                   float* __restrict__ a_dst) {
    int wave = (blockIdx.x * 256 + threadIdx.x) >> 6;
    int lane = threadIdx.x & 63;
    __half2 p = u2h2(h1u[wave * 64 + lane]);
    float h0 = __low2float(p), h1v = __high2float(p);
    float2 sw = *(const float2*)(as_w + lane * 2);
    float2 dw = *(const float2*)(ad_w + lane * 2);
    float ps = h0 * sw.x + h1v * sw.y;
    float pd = h0 * dw.x + h1v * dw.y;
    #pragma unroll
    for (int m = 1; m < 16; m <<= 1) {
        ps += __shfl_xor(ps, m);
        pd += __shfl_xor(pd, m);
    }
    if ((lane & 15) == 0) {
        a_src[wave * 4 + (lane >> 4)] = ps;
        a_dst[wave * 4 + (lane >> 4)] = pd;
    }
}

__global__ __launch_bounds__(256) void att2_kernel(const __half* __restrict__ h2h,
                                                   const float* __restrict__ as_w,
                                                   const float* __restrict__ ad_w,
                                                   float* __restrict__ a_src,
                                                   float* __restrict__ a_dst) {
    int wave = (blockIdx.x * 256 + threadIdx.x) >> 6;
    int lane = threadIdx.x & 63;
    float v = __half2float(h2h[wave * 64 + lane]);
    float ps = v * as_w[lane];
    float pd = v * ad_w[lane];
    #pragma unroll
    for (int m = 1; m < 64; m <<= 1) {
        ps += __shfl_xor(ps, m);
        pd += __shfl_xor(pd, m);
    }
    if (lane == 0) {
        a_src[wave] = ps;
        a_dst[wave] = pd;
    }
}

// ---------------- edge aggregation: fp16 tables, packed half2 FMA ----------
// agg1: wave per dst node. Batch of 16 edges: lane (quad=head, j16=edge) computes
// shifted w once (0 for invalid lanes -> tail needs no predicate), packs
// (f16(w)<<16)|s. Inner: quad handles edge g*4+quad; lane loads uint4 = 8 f16
// channels; 4 x v_pk_fma_f16. Denom accumulated once per batch in fp32.

__global__ __launch_bounds__(256) void agg1_kernel(const int* __restrict__ row_ptr,
                                                   const int* __restrict__ csr_src,
                                                   const unsigned int* __restrict__ h1u,
                                                   const float* __restrict__ a_src,
                                                   const float* __restrict__ a_dst,
                                                   const float* __restrict__ b1,
                                                   float* __restrict__ x2) {
    int n = (blockIdx.x * 256 + threadIdx.x) >> 6;
    int lane = threadIdx.x & 63;
    int quad = lane >> 4;          // edge-slot / head-for-w role
    int col = lane & 15;           // channel-group role: channels col*8..col*8+7
    int j16 = lane & 15;           // batch-load role
    int hd_c = col >> 2;           // head of this lane's channels
    int src_base = hd_c * 16 + quad;
    float adw = a_dst[n * 4 + quad];
    int e = row_ptr[n], end = row_ptr[n + 1];
    __half2 acc0 = u2h2(0u), acc1 = u2h2(0u), acc2 = u2h2(0u), acc3 = u2h2(0u);
    float denom = 0.f;
    while (e < end) {
        int mb = end - e;
        if (mb > 16) mb = 16;
        int s_l = csr_src[e + (j16 < mb ? j16 : 0)];
        float l = a_src[s_l * 4 + quad] + adw;
        float wv = (j16 < mb) ? lrelu_exp_s(l) : 0.f;
        denom += wv;
        unsigned int pack = ((unsigned int)f2h(wv) << 16) | (unsigned int)s_l;
        #pragma unroll
        for (int g = 0; g < 4; ++g) {
            unsigned int pk = __shfl(pack, src_base + g * 4);
            unsigned int wu = pk >> 16;
            __half2 w2 = u2h2(wu | (wu << 16));
            unsigned int s = pk & 0xffffu;
            uint4 hv = *(const uint4*)(h1u + s * 64 + col * 4);
            acc0 = __hfma2(w2, u2h2(hv.x), acc0);
            acc1 = __hfma2(w2, u2h2(hv.y), acc1);
            acc2 = __hfma2(w2, u2h2(hv.z), acc2);
            acc3 = __hfma2(w2, u2h2(hv.w), acc3);
        }
        e += 16;
    }
    // acc: sum across the 4 quads (same col)
    #pragma unroll
    for (int m = 16; m < 64; m <<= 1) {
        acc0 = __hadd2(acc0, u2h2(__shfl_xor(h22u(acc0), m)));
        acc1 = __hadd2(acc1, u2h2(__shfl_xor(h22u(acc1), m)));
        acc2 = __hadd2(acc2, u2h2(__shfl_xor(h22u(acc2), m)));
        acc3 = __hadd2(acc3, u2h2(__shfl_xor(h22u(acc3), m)));
    }
    // denom: sum within each quad (per-head totals), then pull head hd_c's total
    #pragma unroll
    for (int m = 1; m < 16; m <<= 1) denom += __shfl_xor(denom, m);
    float dfin = __shfl(denom, hd_c * 16);
    if (quad == 0) {
        float inv = 1.f / (dfin + EPS_);
        int c0 = col * 8;
        float v[8];
        v[0] = __low2float(acc0); v[1] = __high2float(acc0);
        v[2] = __low2float(acc1); v[3] = __high2float(acc1);
        v[4] = __low2float(acc2); v[5] = __high2float(acc2);
        v[6] = __low2float(acc3); v[7] = __high2float(acc3);
        float o[8];
        #pragma unroll
        for (int i = 0; i < 8; ++i) {
            float u = v[i] * inv + b1[c0 + i];
            o[i] = 1.f / (1.f + __expf(-u));
        }
        float4* dst = (float4*)(x2 + (size_t)n * 128 + c0);
        dst[0] = make_float4(o[0], o[1], o[2], o[3]);
        dst[1] = make_float4(o[4], o[5], o[6], o[7]);
    }
}

// agg2: 8-lane groups, single head. h2 row = 32 uints (64 f16).

__global__ __launch_bounds__(256) void agg2_kernel(const int* __restrict__ row_ptr,
                                                   const int* __restrict__ csr_src,
                                                   const unsigned int* __restrict__ h2u,
                                                   const float* __restrict__ a_src,
                                                   const float* __restrict__ a_dst,
                                                   const float* __restrict__ b2,
                                                   float* __restrict__ out) {
    int n = (blockIdx.x * 256 + threadIdx.x) >> 6;
    int lane = threadIdx.x & 63;
    int grp = lane >> 3;           // edge-slot role (8 slots)
    int col = lane & 7;            // channels col*8..col*8+7
    int j16 = lane & 15;
    float ad = a_dst[n];
    int e = row_ptr[n], end = row_ptr[n + 1];
    __half2 acc0 = u2h2(0u), acc1 = u2h2(0u), acc2 = u2h2(0u), acc3 = u2h2(0u);
    float denom = 0.f;
    while (e < end) {
        int mb = end - e;
        if (mb > 16) mb = 16;
        int s_l = csr_src[e + (j16 < mb ? j16 : 0)];
        float l = a_src[s_l] + ad;
        float wv = (j16 < mb) ? lrelu_exp_s(l) : 0.f;
        denom += wv;
        unsigned int pack = ((unsigned int)f2h(wv) << 16) | (unsigned int)s_l;
        #pragma unroll
        for (int g = 0; g < 2; ++g) {
            unsigned int pk = __shfl(pack, g * 8 + grp);
            unsigned int wu = pk >> 16;
            __half2 w2 = u2h2(wu | (wu << 16));
            unsigned int s = pk & 0xffffu;
            uint4 hv = *(const uint4*)(h2u + s * 32 + col * 4);
            acc0 = __hfma2(w2, u2h2(hv.x), acc0);
            acc1 = __hfma2(w2, u2h2(hv.y), acc1);
            acc2 = __hfma2(w2, u2h2(hv.z), acc2);
            acc3 = __hfma2(w2, u2h2(hv.w), acc3);
        }
        e += 16;
    }
    // acc: sum across the 8 groups (same col)
    #pragma unroll
    for (int m = 8; m < 64; m <<= 1) {
        acc0 = __hadd2(acc0, u2h2(__shfl_xor(h22u(acc0), m)));
        acc1 = __hadd2(acc1, u2h2(__shfl_xor(h22u(acc1), m)));
        acc2 = __hadd2(acc2, u2h2(__shfl_xor(h22u(acc2), m)));
        acc3 = __hadd2(acc3, u2h2(__shfl_xor(h22u(acc3), m)));
    }
    // denom: sum over the 16 batch lanes (identical in every 16-group)
    #pragma unroll
    for (int m = 1; m < 16; m <<= 1) denom += __shfl_xor(denom, m);
    if (lane < 8) {
        float inv = 1.f / (denom + EPS_);
        int c0 = col * 8;
        float v[8];
        v[0] = __low2float(acc0); v[1] = __high2float(acc0);
        v[2] = __low2float(acc1); v[3] = __high2float(acc1);
        v[4] = __low2float(acc2); v[5] = __high2float(acc2);
        v[6] = __low2float(acc3); v[7] = __high2float(acc3);
        float o[8];
        #pragma unroll
        for (int i = 0; i < 8; ++i) {
            float u = v[i] * inv + b2[c0 + i];
            o[i] = 1.f / (1.f + __expf(-u));
        }
        float4* dst = (float4*)(out + (size_t)n * 64 + c0);
        dst[0] = make_float4(o[0], o[1], o[2], o[3]);
        dst[1] = make_float4(o[4], o[5], o[6], o[7]);
    }
}

// ---------------- launch ----------------

extern "C" void kernel_launch(void* const* d_in, const int* in_sizes, int n_in,
                              void* d_out, int out_size, void* d_ws, size_t ws_size,
                              hipStream_t stream) {
    (void)in_sizes; (void)n_in; (void)out_size; (void)ws_size;
    const float* x   = (const float*)d_in[0];
    const int*   ei  = (const int*)d_in[1];
    const float* W1  = (const float*)d_in[2];
    const float* as1 = (const float*)d_in[3];
    const float* ad1 = (const float*)d_in[4];
    const float* b1  = (const float*)d_in[5];
    const float* W2  = (const float*)d_in[6];
    const float* as2 = (const float*)d_in[7];
    const float* ad2 = (const float*)d_in[8];
    const float* b2  = (const float*)d_in[9];
    float* out = (float*)d_out;

    char* p = (char*)d_ws;
    auto alloc = [&](size_t bytes) -> void* {
        void* r = (void*)p;
        p += (bytes + 255) & ~(size_t)255;
        return r;
    };
    int* hist_mat   = (int*)alloc((size_t)NBUCK * PBLOCKS * 4);
    int* cursor_mat = (int*)alloc((size_t)NBUCK * PBLOCKS * 4);
    int* bsum       = (int*)alloc(64 * 4);
    unsigned int* edge_part = (unsigned int*)alloc((size_t)N_EDGES * 4);
    int* row_ptr    = (int*)alloc((size_t)(N_NODES + 1) * 4);
    int* csr_src    = (int*)alloc((size_t)N_EDGES * 4);
    unsigned short* h1 = (unsigned short*)alloc((size_t)N_NODES * 128 * 2);  // fp16
    float* a_src1   = (float*)alloc((size_t)N_NODES * 4 * 4);
    float* a_dst1   = (float*)alloc((size_t)N_NODES * 4 * 4);
    float* x2       = (float*)alloc((size_t)N_NODES * 128 * 4);
    unsigned short* h2 = (unsigned short*)alloc((size_t)N_NODES * 64 * 2);   // fp16
    float* a_src2   = (float*)alloc((size_t)N_NODES * 4);
    float* a_dst2   = (float*)alloc((size_t)N_NODES * 4);

    // CSR build (atomic-free radix partition)
    coarse_hist<<<PBLOCKS, 256, 0, stream>>>(ei, hist_mat);
    scan_a<<<64, 1024, 0, stream>>>(hist_mat, cursor_mat, bsum);
    scan_c<<<64, 1024, 0, stream>>>(cursor_mat, bsum);
    partition_kernel<<<PBLOCKS, 256, 0, stream>>>(ei, cursor_mat, edge_part);
    finalize_kernel<<<NBUCK, 256, 0, stream>>>(edge_part, cursor_mat, row_ptr, csr_src);

    // layer 1
    gemm_mfma<128><<<N_NODES / 64, 256, 128 * 128 * 2, stream>>>(x, W1, h1);
    att1_kernel<<<N_NODES / 4, 256, 0, stream>>>((const unsigned int*)h1, as1, ad1, a_src1, a_dst1);
    agg1_kernel<<<N_NODES / 4, 256, 0, stream>>>(row_ptr, csr_src, (const unsigned int*)h1,
                                                 a_src1, a_dst1, b1, x2);

    // layer 2
    gemm_mfma<64><<<N_NODES / 64, 256, 128 * 64 * 2, stream>>>(x2, W2, h2);
    att2_kernel<<<N_NODES / 4, 256, 0, stream>>>((const __half*)h2, as2, ad2, a_src2, a_dst2);
    agg2_kernel<<<N_NODES / 4, 256, 0, stream>>>(row_ptr, csr_src, (const unsigned int*)h2,
                                                 a_src2, a_dst2, b2, out);
}

// Round 13
// 249.035 us; speedup vs baseline: 1.5127x; 1.0377x over previous
//
#include <hip/hip_runtime.h>
#include <hip/hip_fp16.h>

#define N_NODES 65536
#define N_EDGES 1048576
#define NBUCK 256                 // coarse buckets (dst>>8), 256 nodes each
#define PBLOCKS 256               // partition blocks
#define EPB (N_EDGES / PBLOCKS)   // 4096 edges per partition block
#define K4CAP 6144                // finalize LDS staging capacity (mean 4096, sigma 64)
constexpr float NEG = 0.2f;
constexpr float EPS_ = 1e-16f;
constexpr float WSHIFT = 2.7725887f;   // ln(16): softmax-invariant shift, fp16 overflow guard

typedef __attribute__((ext_vector_type(8))) short bf16x8;
typedef __attribute__((ext_vector_type(4))) float f32x4;

// bf16 helpers (for MFMA fragments / bf16 x2)
__device__ __forceinline__ unsigned short f2bf(float f) {
    unsigned int u = __float_as_uint(f);
    return (unsigned short)((u + 0x7fffu + ((u >> 16) & 1u)) >> 16);
}
// fp16 helpers
__device__ __forceinline__ unsigned short f2h(float f) {
    __half_raw r = __half_raw(__float2half(f));
    return r.x;
}
__device__ __forceinline__ __half2 u2h2(unsigned int u) {
    union { unsigned int u; __half2 h; } c; c.u = u; return c.h;
}
__device__ __forceinline__ unsigned int h22u(__half2 h) {
    union { unsigned int u; __half2 h; } c; c.h = h; return c.u;
}
__device__ __forceinline__ float lrelu_exp_s(float l) {
    return __expf(fmaxf(l, NEG * l) - WSHIFT);
}

// ---------------- CSR build: radix partition by dst>>8, no global atomics ----------------

__global__ __launch_bounds__(256) void coarse_hist(const int* __restrict__ ei,
                                                   int* __restrict__ hist_mat) {
    __shared__ int h[NBUCK];
    int t = threadIdx.x;
    h[t] = 0;
    __syncthreads();
    int base = blockIdx.x * EPB;
    #pragma unroll
    for (int i = 0; i < EPB / 256; ++i) {
        int d = ei[N_EDGES + base + i * 256 + t];
        atomicAdd(&h[d >> 8], 1);
    }
    __syncthreads();
    hist_mat[t * PBLOCKS + blockIdx.x] = h[t];
}

__global__ __launch_bounds__(1024) void scan_a(const int* __restrict__ in,
                                               int* __restrict__ out,
                                               int* __restrict__ bsum) {
    __shared__ int sm[1024];
    int t = threadIdx.x, i = blockIdx.x * 1024 + t;
    int v = in[i];
    sm[t] = v;
    __syncthreads();
    for (int off = 1; off < 1024; off <<= 1) {
        int u = (t >= off) ? sm[t - off] : 0;
        __syncthreads();
        sm[t] += u;
        __syncthreads();
    }
    out[i] = sm[t] - v;
    if (t == 1023) bsum[blockIdx.x] = sm[t];
}

__global__ __launch_bounds__(1024) void scan_c(int* __restrict__ arr,
                                               const int* __restrict__ bsum) {
    __shared__ int off[64];
    int t = threadIdx.x;
    if (t < 64) {
        int v = bsum[t];
        int incl = v;
        #pragma unroll
        for (int o = 1; o < 64; o <<= 1) {
            int u = __shfl_up(incl, o);
            if (t >= o) incl += u;
        }
        off[t] = incl - v;
    }
    __syncthreads();
    int i = blockIdx.x * 1024 + t;
    arr[i] += off[blockIdx.x];
}

__global__ __launch_bounds__(256) void partition_kernel(const int* __restrict__ ei,
                                                        const int* __restrict__ cursor_mat,
                                                        unsigned int* __restrict__ edge_part) {
    __shared__ int h[NBUCK];
    __shared__ int start[NBUCK];
    __shared__ int cur[NBUCK];
    __shared__ int gcur[NBUCK];
    __shared__ unsigned int stage[EPB];
    int t = threadIdx.x;
    h[t] = 0;
    gcur[t] = cursor_mat[t * PBLOCKS + blockIdx.x];
    __syncthreads();
    unsigned int ent[EPB / 256];
    int base = blockIdx.x * EPB;
    #pragma unroll
    for (int i = 0; i < EPB / 256; ++i) {
        int e = base + i * 256 + t;
        int s = ei[e], d = ei[N_EDGES + e];
        ent[i] = ((unsigned int)s << 16) | (unsigned int)d;   // src,dst both < 2^16
        atomicAdd(&h[d >> 8], 1);
    }
    __syncthreads();
    int v = h[t];
    start[t] = v;
    __syncthreads();
    for (int off = 1; off < 256; off <<= 1) {
        int u = (t >= off) ? start[t - off] : 0;
        __syncthreads();
        start[t] += u;
        __syncthreads();
    }
    int excl = start[t] - v;
    start[t] = excl;
    cur[t] = excl;
    __syncthreads();
    #pragma unroll
    for (int i = 0; i < EPB / 256; ++i) {
        int b = (int)((ent[i] & 0xffffu) >> 8);
        int slot = atomicAdd(&cur[b], 1);
        stage[slot] = ent[i];
    }
    __syncthreads();
    int s0 = t * (EPB / 256);
    #pragma unroll
    for (int i = 0; i < EPB / 256; ++i) {
        unsigned int p = stage[s0 + i];
        int b = (int)((p & 0xffffu) >> 8);
        edge_part[gcur[b] + (s0 + i - start[b])] = p;
    }
}

__global__ __launch_bounds__(256) void finalize_kernel(const unsigned int* __restrict__ edge_part,
                                                       const int* __restrict__ cursor_mat,
                                                       int* __restrict__ row_ptr,
                                                       int* __restrict__ csr_src) {
    __shared__ int h[256];
    __shared__ int sc[256];
    __shared__ int cur[256];
    __shared__ unsigned short stage[K4CAP];
    int t = threadIdx.x;
    int b = blockIdx.x;
    if (b == NBUCK - 1 && t == 0) row_ptr[N_NODES] = N_EDGES;
    int cs = cursor_mat[b * PBLOCKS];
    int ce = (b == NBUCK - 1) ? N_EDGES : cursor_mat[(b + 1) * PBLOCKS];
    int cnt = ce - cs;
    h[t] = 0;
    __syncthreads();
    for (int i = t; i < cnt; i += 256)
        atomicAdd(&h[edge_part[cs + i] & 0xffu], 1);
    __syncthreads();
    int v = h[t];
    sc[t] = v;
    __syncthreads();
    for (int off = 1; off < 256; off <<= 1) {
        int u = (t >= off) ? sc[t - off] : 0;
        __syncthreads();
        sc[t] += u;
        __syncthreads();
    }
    int excl = sc[t] - v;
    row_ptr[b * 256 + t] = cs + excl;
    cur[t] = excl;
    __syncthreads();
    if (cnt <= K4CAP) {
        for (int i = t; i < cnt; i += 256) {
            unsigned int p = edge_part[cs + i];
            int slot = atomicAdd(&cur[p & 0xffu], 1);
            stage[slot] = (unsigned short)(p >> 16);
        }
        __syncthreads();
        for (int i = t; i < cnt; i += 256)
            csr_src[cs + i] = (int)stage[i];
    } else {
        for (int i = t; i < cnt; i += 256) {
            unsigned int p = edge_part[cs + i];
            int slot = atomicAdd(&cur[p & 0xffu], 1);
            csr_src[cs + slot] = (int)(p >> 16);
        }
    }
}

// ---------------- GEMM via MFMA 16x16x32 bf16 (fp32 accum, fp16 out) ----------------
// layer 1: fp32 X input (convert to bf16 A-frags in-register)

__global__ __launch_bounds__(256) void gemm1_mfma(const float* __restrict__ X,
                                                  const float* __restrict__ W,
                                                  unsigned short* __restrict__ H) {
    constexpr int OUTC = 128;
    constexpr int NT = OUTC / 16;
    extern __shared__ unsigned short Wl[];
    int t = threadIdx.x;
    for (int idx = t; idx < OUTC * 128; idx += 256) {
        int j = idx & 7;
        int ln = (idx >> 3) & 63;
        int fc = idx >> 9;
        int kc = fc & 3, ct = fc >> 2;
        int k = kc * 32 + (ln >> 4) * 8 + j;
        int n = ct * 16 + (ln & 15);
        Wl[idx] = (unsigned short)f2bf(W[k * OUTC + n]);
    }
    __syncthreads();
    int wave = t >> 6, lane = t & 63;
    int m = lane & 15, quad = lane >> 4;
    int node_base = blockIdx.x * 64 + wave * 16;
    const float* xrow = X + (size_t)(node_base + m) * 128 + quad * 8;
    bf16x8 a[4];
    #pragma unroll
    for (int kc = 0; kc < 4; ++kc) {
        float4 u = *(const float4*)(xrow + kc * 32);
        float4 v = *(const float4*)(xrow + kc * 32 + 4);
        bf16x8 af;
        af[0] = (short)f2bf(u.x); af[1] = (short)f2bf(u.y);
        af[2] = (short)f2bf(u.z); af[3] = (short)f2bf(u.w);
        af[4] = (short)f2bf(v.x); af[5] = (short)f2bf(v.y);
        af[6] = (short)f2bf(v.z); af[7] = (short)f2bf(v.w);
        a[kc] = af;
    }
    #pragma unroll
    for (int ct = 0; ct < NT; ++ct) {
        f32x4 acc = {0.f, 0.f, 0.f, 0.f};
        #pragma unroll
        for (int kc = 0; kc < 4; ++kc) {
            bf16x8 bfr = *(const bf16x8*)(Wl + ((ct * 4 + kc) * 64 + lane) * 8);
            acc = __builtin_amdgcn_mfma_f32_16x16x32_bf16(a[kc], bfr, acc, 0, 0, 0);
        }
        #pragma unroll
        for (int r = 0; r < 4; ++r) {
            int row = quad * 4 + r;
            H[(size_t)(node_base + row) * OUTC + ct * 16 + m] = f2h(acc[r]);
        }
    }
}

// layer 2: bf16 X input (direct A-frag vector loads, zero conversion)

__global__ __launch_bounds__(256) void gemm2_mfma(const unsigned short* __restrict__ X,
                                                  const float* __restrict__ W,
                                                  unsigned short* __restrict__ H) {
    constexpr int OUTC = 64;
    constexpr int NT = OUTC / 16;
    extern __shared__ unsigned short Wl[];
    int t = threadIdx.x;
    for (int idx = t; idx < OUTC * 128; idx += 256) {
        int j = idx & 7;
        int ln = (idx >> 3) & 63;
        int fc = idx >> 9;
        int kc = fc & 3, ct = fc >> 2;
        int k = kc * 32 + (ln >> 4) * 8 + j;
        int n = ct * 16 + (ln & 15);
        Wl[idx] = (unsigned short)f2bf(W[k * OUTC + n]);
    }
    __syncthreads();
    int wave = t >> 6, lane = t & 63;
    int m = lane & 15, quad = lane >> 4;
    int node_base = blockIdx.x * 64 + wave * 16;
    const unsigned short* xrow = X + (size_t)(node_base + m) * 128 + quad * 8;
    bf16x8 a[4];
    #pragma unroll
    for (int kc = 0; kc < 4; ++kc) a[kc] = *(const bf16x8*)(xrow + kc * 32);
    #pragma unroll
    for (int ct = 0; ct < NT; ++ct) {
        f32x4 acc = {0.f, 0.f, 0.f, 0.f};
        #pragma unroll
        for (int kc = 0; kc < 4; ++kc) {
            bf16x8 bfr = *(const bf16x8*)(Wl + ((ct * 4 + kc) * 64 + lane) * 8);
            acc = __builtin_amdgcn_mfma_f32_16x16x32_bf16(a[kc], bfr, acc, 0, 0, 0);
        }
        #pragma unroll
        for (int r = 0; r < 4; ++r) {
            int row = quad * 4 + r;
            H[(size_t)(node_base + row) * OUTC + ct * 16 + m] = f2h(acc[r]);
        }
    }
}

// ---------------- attention logits (fp16 h) ----------------

__global__ __launch_bounds__(256) void att1_kernel(const unsigned int* __restrict__ h1u,
                                                   const float* __restrict__ as_w,
                                                   const float* __restrict__ ad_w,
                                                   float* __restrict__ a_src,
                                                   float* __restrict__ a_dst) {
    int wave = (blockIdx.x * 256 + threadIdx.x) >> 6;
    int lane = threadIdx.x & 63;
    __half2 p = u2h2(h1u[wave * 64 + lane]);
    float h0 = __low2float(p), h1v = __high2float(p);
    float2 sw = *(const float2*)(as_w + lane * 2);
    float2 dw = *(const float2*)(ad_w + lane * 2);
    float ps = h0 * sw.x + h1v * sw.y;
    float pd = h0 * dw.x + h1v * dw.y;
    #pragma unroll
    for (int m = 1; m < 16; m <<= 1) {
        ps += __shfl_xor(ps, m);
        pd += __shfl_xor(pd, m);
    }
    if ((lane & 15) == 0) {
        a_src[wave * 4 + (lane >> 4)] = ps;
        a_dst[wave * 4 + (lane >> 4)] = pd;
    }
}

__global__ __launch_bounds__(256) void att2_kernel(const __half* __restrict__ h2h,
                                                   const float* __restrict__ as_w,
                                                   const float* __restrict__ ad_w,
                                                   float* __restrict__ a_src,
                                                   float* __restrict__ a_dst) {
    int wave = (blockIdx.x * 256 + threadIdx.x) >> 6;
    int lane = threadIdx.x & 63;
    float v = __half2float(h2h[wave * 64 + lane]);
    float ps = v * as_w[lane];
    float pd = v * ad_w[lane];
    #pragma unroll
    for (int m = 1; m < 64; m <<= 1) {
        ps += __shfl_xor(ps, m);
        pd += __shfl_xor(pd, m);
    }
    if (lane == 0) {
        a_src[wave] = ps;
        a_dst[wave] = pd;
    }
}

// ---------------- edge aggregation: TWO nodes per wave (half-wave each) ----------
// agg1: half-wave (32 lanes) per dst node -> 2 independent gather chains/wave.
// Batch = 8 edges: w-lane (whead=ln>>3, j8=ln&7) computes shifted w, packs
// (f16(w)<<16)|s. Inner: 2 row-slots (sub=ln>>4) x 16 col-lanes; 4 g-iters.
// Output x2 in bf16 (feeds gemm2 A-frags directly).

__global__ __launch_bounds__(256) void agg1_kernel(const int* __restrict__ row_ptr,
                                                   const int* __restrict__ csr_src,
                                                   const unsigned int* __restrict__ h1u,
                                                   const float* __restrict__ a_src,
                                                   const float* __restrict__ a_dst,
                                                   const float* __restrict__ b1,
                                                   unsigned short* __restrict__ x2) {
    int wave = (blockIdx.x * 256 + threadIdx.x) >> 6;
    int lane = threadIdx.x & 63;
    int half = lane >> 5;
    int ln = lane & 31;
    int n = wave * 2 + half;
    int j8 = ln & 7;               // batch edge slot
    int whead = ln >> 3;           // head for w-compute
    int sub = ln >> 4;             // row-slot within half (0/1)
    int col = ln & 15;             // channel group: ch col*8..+7
    int hd_c = col >> 2;           // head of this lane's channels
    int rbase = half * 32 + hd_c * 8 + sub;   // pack-lane base (+ g*2)
    float adw = a_dst[n * 4 + whead];
    int e = row_ptr[n], end = row_ptr[n + 1];
    __half2 acc0 = u2h2(0u), acc1 = u2h2(0u), acc2 = u2h2(0u), acc3 = u2h2(0u);
    float denom = 0.f;
    while (e < end) {
        int mb = end - e;
        if (mb > 8) mb = 8;
        int s_l = csr_src[e + (j8 < mb ? j8 : 0)];
        float l = a_src[s_l * 4 + whead] + adw;
        float wv = (j8 < mb) ? lrelu_exp_s(l) : 0.f;
        denom += wv;
        unsigned int pack = ((unsigned int)f2h(wv) << 16) | (unsigned int)s_l;
        #pragma unroll
        for (int g = 0; g < 4; ++g) {
            unsigned int pk = __shfl(pack, rbase + g * 2);
            unsigned int wu = pk >> 16;
            __half2 w2 = u2h2(wu | (wu << 16));
            unsigned int s = pk & 0xffffu;
            uint4 hv = *(const uint4*)(h1u + s * 64 + col * 4);
            acc0 = __hfma2(w2, u2h2(hv.x), acc0);
            acc1 = __hfma2(w2, u2h2(hv.y), acc1);
            acc2 = __hfma2(w2, u2h2(hv.z), acc2);
            acc3 = __hfma2(w2, u2h2(hv.w), acc3);
        }
        e += 8;
    }
    // acc: sum the 2 row-slots (xor 16 stays within half)
    acc0 = __hadd2(acc0, u2h2(__shfl_xor(h22u(acc0), 16)));
    acc1 = __hadd2(acc1, u2h2(__shfl_xor(h22u(acc1), 16)));
    acc2 = __hadd2(acc2, u2h2(__shfl_xor(h22u(acc2), 16)));
    acc3 = __hadd2(acc3, u2h2(__shfl_xor(h22u(acc3), 16)));
    // denom: reduce over j8 within each 8-lane head group
    #pragma unroll
    for (int m = 1; m < 8; m <<= 1) denom += __shfl_xor(denom, m);
    float dfin = __shfl(denom, half * 32 + hd_c * 8);
    if (sub == 0) {
        float inv = 1.f / (dfin + EPS_);
        int c0 = col * 8;
        float v[8];
        v[0] = __low2float(acc0); v[1] = __high2float(acc0);
        v[2] = __low2float(acc1); v[3] = __high2float(acc1);
        v[4] = __low2float(acc2); v[5] = __high2float(acc2);
        v[6] = __low2float(acc3); v[7] = __high2float(acc3);
        unsigned int o[4];
        #pragma unroll
        for (int i = 0; i < 4; ++i) {
            float u0 = v[2 * i] * inv + b1[c0 + 2 * i];
            float u1 = v[2 * i + 1] * inv + b1[c0 + 2 * i + 1];
            u0 = 1.f / (1.f + __expf(-u0));
            u1 = 1.f / (1.f + __expf(-u1));
            o[i] = (unsigned int)f2bf(u0) | ((unsigned int)f2bf(u1) << 16);
        }
        *(uint4*)(x2 + (size_t)n * 128 + c0) = make_uint4(o[0], o[1], o[2], o[3]);
    }
}

// agg2: half-wave per node; 4 row-slots (sub=(ln>>3)&3) x 8 col-lanes; batch = 8.

__global__ __launch_bounds__(256) void agg2_kernel(const int* __restrict__ row_ptr,
                                                   const int* __restrict__ csr_src,
                                                   const unsigned int* __restrict__ h2u,
                                                   const float* __restrict__ a_src,
                                                   const float* __restrict__ a_dst,
                                                   const float* __restrict__ b2,
                                                   float* __restrict__ out) {
    int wave = (blockIdx.x * 256 + threadIdx.x) >> 6;
    int lane = threadIdx.x & 63;
    int half = lane >> 5;
    int ln = lane & 31;
    int n = wave * 2 + half;
    int j8 = ln & 7;
    int sub = (ln >> 3) & 3;       // row-slot (4 per half)
    int col = ln & 7;              // channel group: ch col*8..+7
    int rbase = half * 32 + sub;   // pack lane (+ g*4)
    float ad = a_dst[n];
    int e = row_ptr[n], end = row_ptr[n + 1];
    __half2 acc0 = u2h2(0u), acc1 = u2h2(0u), acc2 = u2h2(0u), acc3 = u2h2(0u);
    float denom = 0.f;
    while (e < end) {
        int mb = end - e;
        if (mb > 8) mb = 8;
        int s_l = csr_src[e + (j8 < mb ? j8 : 0)];
        float l = a_src[s_l] + ad;
        float wv = (j8 < mb) ? lrelu_exp_s(l) : 0.f;
        denom += wv;
        unsigned int pack = ((unsigned int)f2h(wv) << 16) | (unsigned int)s_l;
        #pragma unroll
        for (int g = 0; g < 2; ++g) {
            unsigned int pk = __shfl(pack, rbase + g * 4);
            unsigned int wu = pk >> 16;
            __half2 w2 = u2h2(wu | (wu << 16));
            unsigned int s = pk & 0xffffu;
            uint4 hv = *(const uint4*)(h2u + s * 32 + col * 4);
            acc0 = __hfma2(w2, u2h2(hv.x), acc0);
            acc1 = __hfma2(w2, u2h2(hv.y), acc1);
            acc2 = __hfma2(w2, u2h2(hv.z), acc2);
            acc3 = __hfma2(w2, u2h2(hv.w), acc3);
        }
        e += 8;
    }
    // acc: sum the 4 row-slots (xor 8,16 stay within half)
    #pragma unroll
    for (int m = 8; m < 32; m <<= 1) {
        acc0 = __hadd2(acc0, u2h2(__shfl_xor(h22u(acc0), m)));
        acc1 = __hadd2(acc1, u2h2(__shfl_xor(h22u(acc1), m)));
        acc2 = __hadd2(acc2, u2h2(__shfl_xor(h22u(acc2), m)));
        acc3 = __hadd2(acc3, u2h2(__shfl_xor(h22u(acc3), m)));
    }
    // denom: reduce over j8 within 8-lane group
    #pragma unroll
    for (int m = 1; m < 8; m <<= 1) denom += __shfl_xor(denom, m);
    if (sub == 0) {
        float inv = 1.f / (denom + EPS_);
        int c0 = col * 8;
        float v[8];
        v[0] = __low2float(acc0); v[1] = __high2float(acc0);
        v[2] = __low2float(acc1); v[3] = __high2float(acc1);
        v[4] = __low2float(acc2); v[5] = __high2float(acc2);
        v[6] = __low2float(acc3); v[7] = __high2float(acc3);
        float o[8];
        #pragma unroll
        for (int i = 0; i < 8; ++i) {
            float u = v[i] * inv + b2[c0 + i];
            o[i] = 1.f / (1.f + __expf(-u));
        }
        float4* dst = (float4*)(out + (size_t)n * 64 + c0);
        dst[0] = make_float4(o[0], o[1], o[2], o[3]);
        dst[1] = make_float4(o[4], o[5], o[6], o[7]);
    }
}

// ---------------- launch ----------------

extern "C" void kernel_launch(void* const* d_in, const int* in_sizes, int n_in,
                              void* d_out, int out_size, void* d_ws, size_t ws_size,
                              hipStream_t stream) {
    (void)in_sizes; (void)n_in; (void)out_size; (void)ws_size;
    const float* x   = (const float*)d_in[0];
    const int*   ei  = (const int*)d_in[1];
    const float* W1  = (const float*)d_in[2];
    const float* as1 = (const float*)d_in[3];
    const float* ad1 = (const float*)d_in[4];
    const float* b1  = (const float*)d_in[5];
    const float* W2  = (const float*)d_in[6];
    const float* as2 = (const float*)d_in[7];
    const float* ad2 = (const float*)d_in[8];
    const float* b2  = (const float*)d_in[9];
    float* out = (float*)d_out;

    char* p = (char*)d_ws;
    auto alloc = [&](size_t bytes) -> void* {
        void* r = (void*)p;
        p += (bytes + 255) & ~(size_t)255;
        return r;
    };
    int* hist_mat   = (int*)alloc((size_t)NBUCK * PBLOCKS * 4);
    int* cursor_mat = (int*)alloc((size_t)NBUCK * PBLOCKS * 4);
    int* bsum       = (int*)alloc(64 * 4);
    unsigned int* edge_part = (unsigned int*)alloc((size_t)N_EDGES * 4);
    int* row_ptr    = (int*)alloc((size_t)(N_NODES + 1) * 4);
    int* csr_src    = (int*)alloc((size_t)N_EDGES * 4);
    unsigned short* h1 = (unsigned short*)alloc((size_t)N_NODES * 128 * 2);  // fp16
    float* a_src1   = (float*)alloc((size_t)N_NODES * 4 * 4);
    float* a_dst1   = (float*)alloc((size_t)N_NODES * 4 * 4);
    unsigned short* x2 = (unsigned short*)alloc((size_t)N_NODES * 128 * 2);  // bf16
    unsigned short* h2 = (unsigned short*)alloc((size_t)N_NODES * 64 * 2);   // fp16
    float* a_src2   = (float*)alloc((size_t)N_NODES * 4);
    float* a_dst2   = (float*)alloc((size_t)N_NODES * 4);

    // CSR build (atomic-free radix partition)
    coarse_hist<<<PBLOCKS, 256, 0, stream>>>(ei, hist_mat);
    scan_a<<<64, 1024, 0, stream>>>(hist_mat, cursor_mat, bsum);
    scan_c<<<64, 1024, 0, stream>>>(cursor_mat, bsum);
    partition_kernel<<<PBLOCKS, 256, 0, stream>>>(ei, cursor_mat, edge_part);
    finalize_kernel<<<NBUCK, 256, 0, stream>>>(edge_part, cursor_mat, row_ptr, csr_src);

    // layer 1
    gemm1_mfma<<<N_NODES / 64, 256, 128 * 128 * 2, stream>>>(x, W1, h1);
    att1_kernel<<<N_NODES / 4, 256, 0, stream>>>((const unsigned int*)h1, as1, ad1, a_src1, a_dst1);
    agg1_kernel<<<N_NODES / 8, 256, 0, stream>>>(row_ptr, csr_src, (const unsigned int*)h1,
                                                 a_src1, a_dst1, b1, x2);

    // layer 2
    gemm2_mfma<<<N_NODES / 64, 256, 128 * 64 * 2, stream>>>(x2, W2, h2);
    att2_kernel<<<N_NODES / 4, 256, 0, stream>>>((const __half*)h2, as2, ad2, a_src2, a_dst2);
    agg2_kernel<<<N_NODES / 8, 256, 0, stream>>>(row_ptr, csr_src, (const unsigned int*)h2,
                                                 a_src2, a_dst2, b2, out);
}